// Round 5
// baseline (655.994 us; speedup 1.0000x reference)
//
#include <hip/hip_runtime.h>
#include <hip/hip_bf16.h>

// R5: counting-sort edges by dst; edge kernels process sorted edges with
// in-register segmented reduction -> ~6x fewer atomic line-packets (the
// measured ~18 G packets/s device-atomic ceiling was binding s2s/a2s).
// Keeps R4's MFMA structure (A=edges, B=weights in LDS frags, bias-via-MFMA,
// conflict-free Z transition).

typedef __attribute__((ext_vector_type(8))) short short8;
typedef __attribute__((ext_vector_type(4))) float f32x4;

#define MFMA(a, b, c) __builtin_amdgcn_mfma_f32_16x16x32_bf16(a, b, c, 0, 0, 0)

union FU { short8 v; unsigned int d[4]; unsigned short us[8]; };

__device__ __forceinline__ unsigned short f2bf(float f) {
    unsigned u = __float_as_uint(f);
    u += 0x7fffu + ((u >> 16) & 1u);   // RNE (data NaN-free)
    return (unsigned short)(u >> 16);
}
__device__ __forceinline__ unsigned int pack2(float a, float b) {
    return (unsigned int)f2bf(a) | ((unsigned int)f2bf(b) << 16);
}
__device__ __forceinline__ float tanh_fast(float xv) {
    float t = __builtin_amdgcn_exp2f(xv * 2.8853900817779268f); // 2*log2(e)
    return 1.0f - 2.0f * __builtin_amdgcn_rcpf(t + 1.0f);
}

template <typename KM>
__device__ void build_frags(const float* __restrict__ w, const float* __restrict__ b,
                            unsigned short* dst, int nchunks, int tid, KM km) {
    int total = nchunks * 4 * 64;
    for (int f = tid; f < total; f += 256) {
        int lv = f & 63, nt = (f >> 6) & 3, c = f >> 8;
        int n = nt * 16 + (lv & 15);
        int kb = c * 32 + ((lv >> 4) << 3);
        unsigned short* o = dst + f * 8;
        #pragma unroll
        for (int j = 0; j < 8; ++j) {
            int sk = km(kb + j);
            float v = (sk >= 0) ? w[sk * 64 + n] : (sk == -1 ? b[n] : 0.f);
            o[j] = f2bf(v);
        }
    }
}

#define PERM_KM [](int k) -> int { return (k >> 2) + 16 * (k & 3); }

// C-layout (lane q,m16 holds row=q*4+r, feat=nt*16+m16) -> Zb[row][kpos],
// kpos = 4*m16 + nt. One b64 write per r; row stride 72 elems.
#define ZTRANS(Zw, accv)                                                       \
    _Pragma("unroll")                                                          \
    for (int r = 0; r < 4; ++r) {                                              \
        uint2 pv;                                                              \
        pv.x = pack2(tanh_fast(accv[0][r]), tanh_fast(accv[1][r]));            \
        pv.y = pack2(tanh_fast(accv[2][r]), tanh_fast(accv[3][r]));            \
        *(uint2*)((Zw) + ((q << 2) + r) * 72 + (m16 << 2)) = pv;               \
    }

// ---------------------------------------------------------------------------
// prep1: bf16 row tables + edge pads + per-dst counts & ranks (both graphs)
// ---------------------------------------------------------------------------
__global__ __launch_bounds__(256) void prep1(
    const float* __restrict__ ps, const float* __restrict__ pa,
    const float* __restrict__ h, const float* __restrict__ x,
    const float* __restrict__ u,
    const int* __restrict__ s2s_dst, const float* __restrict__ s2s_dis,
    const int* __restrict__ a2s_dst, const float* __restrict__ a2s_dis,
    unsigned short* __restrict__ s_row, unsigned short* __restrict__ a_row,
    unsigned short* __restrict__ e_pad_s, unsigned short* __restrict__ e_pad_a,
    int* __restrict__ cnt_s, int* __restrict__ rank_s,
    int* __restrict__ cnt_a, int* __restrict__ rank_a,
    int NS, int NA, int ES, int EA)
{
    int R0 = NS * 80, R1 = R0 + NA * 16, R2 = R1 + ES, R3 = R2 + EA;
    for (int i = blockIdx.x * 256 + threadIdx.x; i < R3; i += gridDim.x * 256) {
        if (i < R0) {
            int n = i / 80, k = i - n * 80;
            float v = (k < 2) ? ps[n * 2 + k] : (k < 10) ? x[n * 8 + k - 2]
                    : (k < 74) ? h[n * 64 + k - 10] : 0.f;
            s_row[i] = f2bf(v);
        } else if (i < R1) {
            int j = i - R0; int a = j / 16, k = j - a * 16;
            float v = (k < 2) ? pa[a * 2 + k] : (k < 10) ? u[a * 8 + k - 2] : 0.f;
            a_row[j] = f2bf(v);
        } else if (i < R2) {
            int e = i - R1; int d = s2s_dst[e];
            uint2 p;
            p.x = (unsigned)f2bf(ps[d * 2]) | ((unsigned)f2bf(ps[d * 2 + 1]) << 16);
            p.y = (unsigned)f2bf(s2s_dis[e]) | (0x3F80u << 16);   // dis, 1.0
            *(uint2*)&e_pad_s[(size_t)e * 4] = p;
            rank_s[e] = atomicAdd(&cnt_s[d], 1);
        } else {
            int e = i - R2; int d = a2s_dst[e];
            uint2 p;
            p.x = (unsigned)f2bf(ps[d * 2]) | ((unsigned)f2bf(ps[d * 2 + 1]) << 16);
            p.y = (unsigned)f2bf(a2s_dis[e]) | (0x3F80u << 16);
            *(uint2*)&e_pad_a[(size_t)e * 4] = p;
            rank_a[e] = atomicAdd(&cnt_a[d], 1);
        }
    }
}

// ---------------------------------------------------------------------------
// scan2: exclusive prefix sums of cnt_s and cnt_a (single block, 1024 thr)
// ---------------------------------------------------------------------------
__global__ __launch_bounds__(1024) void scan2(
    const int* __restrict__ cnt_s, int* __restrict__ off_s,
    const int* __restrict__ cnt_a, int* __restrict__ off_a, int N)
{
    __shared__ int part[1024];
    int t = threadIdx.x;
    int C = (N + 1023) >> 10;
    int lo = t * C, hi = lo + C < N ? lo + C : N;
    for (int pass = 0; pass < 2; ++pass) {
        const int* cnt = pass ? cnt_a : cnt_s;
        int* off = pass ? off_a : off_s;
        int s = 0;
        for (int i = lo; i < hi; ++i) s += cnt[i];
        part[t] = s;
        __syncthreads();
        for (int d = 1; d < 1024; d <<= 1) {
            int v = (t >= d) ? part[t - d] : 0;
            __syncthreads();
            part[t] += v;
            __syncthreads();
        }
        int run = (t > 0) ? part[t - 1] : 0;
        __syncthreads();
        for (int i = lo; i < hi; ++i) { off[i] = run; run += cnt[i]; }
        __syncthreads();
    }
}

// ---------------------------------------------------------------------------
// scatter_sort: materialize dst-sorted src/dst/pad arrays (plain stores)
// ---------------------------------------------------------------------------
__global__ __launch_bounds__(256) void scatter_sort(
    const int* __restrict__ src, const int* __restrict__ dst,
    const int* __restrict__ rank, const int* __restrict__ off,
    const unsigned short* __restrict__ e_pad,
    int* __restrict__ ssrc, int* __restrict__ sdst,
    unsigned short* __restrict__ spad, int E)
{
    for (int i = blockIdx.x * 256 + threadIdx.x; i < E; i += gridDim.x * 256) {
        int d = dst[i];
        int pos = off[d] + rank[i];
        ssrc[pos] = src[i];
        sdst[pos] = d;
        *(uint2*)(spad + (size_t)pos * 4) = *(const uint2*)(e_pad + (size_t)i * 4);
    }
}

// ---------------------------------------------------------------------------
// s2s: sorted edges, K=96 [s_row(80) | psd,dis,1.0,0...], segmented scatter.
// Row map: C-tile mt row m <- sorted pos p0 + 8*(m>>2) + 4*mt + (m&3), so
// lane q's 8 rows (both mt) are consecutive sorted edges p0+8q..p0+8q+7.
// ---------------------------------------------------------------------------
__global__ __launch_bounds__(256) void s2s_mfma(
    const unsigned short* __restrict__ s_row,
    const int* __restrict__ ssrc, const int* __restrict__ sdst,
    const unsigned short* __restrict__ spad,
    const float* __restrict__ w1, const float* __restrict__ b1,
    const float* __restrict__ w2, const float* __restrict__ b2,
    const float* __restrict__ w3, const float* __restrict__ b3,
    float* __restrict__ sum_x, int E)
{
    __shared__ __align__(16) unsigned short B1[3 * 4 * 64 * 8];
    __shared__ __align__(16) unsigned short B2[2 * 4 * 64 * 8];
    __shared__ __align__(16) unsigned short B3[2 * 4 * 64 * 8];
    __shared__ __align__(16) unsigned short Z[4][16 * 72];

    int tid = threadIdx.x;
    build_frags(w1, b1, B1, 3, tid, [](int k) -> int {
        if (k < 2)   return k;
        if (k < 74)  return k + 3;
        if (k < 80)  return -2;
        if (k < 82)  return k - 78;
        if (k == 82) return 4;
        if (k == 83) return -1;
        return -2; });
    build_frags(w2, b2, B2, 2, tid, PERM_KM);
    build_frags(w3, b3, B3, 2, tid, PERM_KM);
    __syncthreads();

    int wid = tid >> 6, lane = tid & 63, m16 = lane & 15, q = lane >> 4;
    unsigned short* Zw = Z[wid];

    FU onesf; onesf.d[0] = (q == 0) ? 0x3F80u : 0u; onesf.d[1] = 0; onesf.d[2] = 0; onesf.d[3] = 0;
    unsigned int b2d[4], b3d[4];
    #pragma unroll
    for (int nt = 0; nt < 4; ++nt) {
        b2d[nt] = (q == 0) ? (unsigned)f2bf(b2[nt * 16 + m16]) : 0u;
        b3d[nt] = (q == 0) ? (unsigned)f2bf(b3[nt * 16 + m16]) : 0u;
    }

    int T = E >> 5;
    for (int t = blockIdx.x * 4 + wid; t < T; t += gridDim.x * 4) {
        int p0 = t * 32;
        int sp0 = p0 + ((m16 >> 2) << 3) + (m16 & 3);  // mt=0 A row
        int sp1 = sp0 + 4;                              // mt=1 A row
        int s0 = ssrc[sp0], s1 = ssrc[sp1];
        int pb = p0 + (q << 3);
        int dseq[8];
        #pragma unroll
        for (int j = 0; j < 8; ++j) dseq[j] = sdst[pb + j];

        FU Lb[2][3]; uint2 ep[2];
        const unsigned short* rA = s_row + (size_t)s0 * 80;
        const unsigned short* rB = s_row + (size_t)s1 * 80;
        #pragma unroll
        for (int c = 0; c < 3; ++c) {
            Lb[0][c].v = *(const short8*)(rA + c * 32 + q * 8);
            Lb[1][c].v = *(const short8*)(rB + c * 32 + q * 8);
        }
        ep[0] = *(const uint2*)(spad + (size_t)sp0 * 4);
        ep[1] = *(const uint2*)(spad + (size_t)sp1 * 4);
        #pragma unroll
        for (int mt = 0; mt < 2; ++mt) {            // chunk 2: q2=pad, q3=0
            FU f = Lb[mt][2];
            f.d[0] = q < 2 ? f.d[0] : (q == 2 ? ep[mt].x : 0u);
            f.d[1] = q < 2 ? f.d[1] : (q == 2 ? ep[mt].y : 0u);
            f.d[2] = q < 2 ? f.d[2] : 0u;
            f.d[3] = q < 2 ? f.d[3] : 0u;
            Lb[mt][2] = f;
        }

        f32x4 acc1[2][4];
        #pragma unroll
        for (int mt = 0; mt < 2; ++mt)
            #pragma unroll
            for (int nt = 0; nt < 4; ++nt) acc1[mt][nt] = (f32x4){0.f, 0.f, 0.f, 0.f};
        #pragma unroll
        for (int c = 0; c < 3; ++c)
            #pragma unroll
            for (int nt = 0; nt < 4; ++nt) {
                short8 wf = *(const short8*)(B1 + ((c * 4 + nt) * 64 + lane) * 8);
                acc1[0][nt] = MFMA(Lb[0][c].v, wf, acc1[0][nt]);
                acc1[1][nt] = MFMA(Lb[1][c].v, wf, acc1[1][nt]);
            }

        f32x4 a3[2][4];
        #pragma unroll
        for (int mt = 0; mt < 2; ++mt) {
            ZTRANS(Zw, acc1[mt])
            FU A2[2];
            A2[0].v = *(const short8*)(Zw + m16 * 72 + 0 * 32 + q * 8);
            A2[1].v = *(const short8*)(Zw + m16 * 72 + 1 * 32 + q * 8);

            f32x4 a2[4];
            #pragma unroll
            for (int nt = 0; nt < 4; ++nt) {
                a2[nt] = (f32x4){0.f, 0.f, 0.f, 0.f};
                short8 w0 = *(const short8*)(B2 + ((0 * 4 + nt) * 64 + lane) * 8);
                short8 w1f = *(const short8*)(B2 + ((1 * 4 + nt) * 64 + lane) * 8);
                a2[nt] = MFMA(A2[0].v, w0, a2[nt]);
                a2[nt] = MFMA(A2[1].v, w1f, a2[nt]);
                FU bf; bf.d[0] = b2d[nt]; bf.d[1] = 0; bf.d[2] = 0; bf.d[3] = 0;
                a2[nt] = MFMA(onesf.v, bf.v, a2[nt]);
            }

            ZTRANS(Zw, a2)
            FU A3[2];
            A3[0].v = *(const short8*)(Zw + m16 * 72 + 0 * 32 + q * 8);
            A3[1].v = *(const short8*)(Zw + m16 * 72 + 1 * 32 + q * 8);

            #pragma unroll
            for (int nt = 0; nt < 4; ++nt) {
                a3[mt][nt] = (f32x4){0.f, 0.f, 0.f, 0.f};
                short8 w0 = *(const short8*)(B3 + ((0 * 4 + nt) * 64 + lane) * 8);
                short8 w1f = *(const short8*)(B3 + ((1 * 4 + nt) * 64 + lane) * 8);
                a3[mt][nt] = MFMA(A3[0].v, w0, a3[mt][nt]);
                a3[mt][nt] = MFMA(A3[1].v, w1f, a3[mt][nt]);
                FU bf; bf.d[0] = b3d[nt]; bf.d[1] = 0; bf.d[2] = 0; bf.d[3] = 0;
                a3[mt][nt] = MFMA(onesf.v, bf.v, a3[mt][nt]);
            }
        }

        // segmented emit over 8 consecutive sorted edges (j = 4*mt + r)
        bool eq[7];
        #pragma unroll
        for (int j = 0; j < 7; ++j) eq[j] = (dseq[j] == dseq[j + 1]);
        #pragma unroll
        for (int nt = 0; nt < 4; ++nt) {
            float v[8];
            #pragma unroll
            for (int mt = 0; mt < 2; ++mt)
                #pragma unroll
                for (int r = 0; r < 4; ++r) v[mt * 4 + r] = a3[mt][nt][r];
            #pragma unroll
            for (int j = 0; j < 7; ++j) {
                if (eq[j]) v[j + 1] += v[j];
                else unsafeAtomicAdd(&sum_x[(size_t)dseq[j] * 64 + nt * 16 + m16], v[j]);
            }
            unsafeAtomicAdd(&sum_x[(size_t)dseq[7] * 64 + nt * 16 + m16], v[7]);
        }
    }
}

// ---------------------------------------------------------------------------
// a2s: sorted edges, K=32 [a_row(16) | psd,dis,1.0,0...], segmented scatter.
// ---------------------------------------------------------------------------
__global__ __launch_bounds__(256) void a2s_mfma(
    const unsigned short* __restrict__ a_row,
    const int* __restrict__ ssrc, const int* __restrict__ sdst,
    const unsigned short* __restrict__ spad,
    const float* __restrict__ w1, const float* __restrict__ b1,
    const float* __restrict__ w2, const float* __restrict__ b2,
    const float* __restrict__ w3, const float* __restrict__ b3,
    float* __restrict__ sum_u, int E)
{
    __shared__ __align__(16) unsigned short B1[1 * 4 * 64 * 8];
    __shared__ __align__(16) unsigned short B2[2 * 4 * 64 * 8];
    __shared__ __align__(16) unsigned short B3[2 * 4 * 64 * 8];
    __shared__ __align__(16) unsigned short Z[4][16 * 72];

    int tid = threadIdx.x;
    build_frags(w1, b1, B1, 1, tid, [](int k) -> int {
        if (k < 2)   return k;
        if (k < 10)  return k + 3;
        if (k < 16)  return -2;
        if (k < 18)  return k - 14;
        if (k == 18) return 4;
        if (k == 19) return -1;
        return -2; });
    build_frags(w2, b2, B2, 2, tid, PERM_KM);
    build_frags(w3, b3, B3, 2, tid, PERM_KM);
    __syncthreads();

    int wid = tid >> 6, lane = tid & 63, m16 = lane & 15, q = lane >> 4;
    unsigned short* Zw = Z[wid];

    FU onesf; onesf.d[0] = (q == 0) ? 0x3F80u : 0u; onesf.d[1] = 0; onesf.d[2] = 0; onesf.d[3] = 0;
    unsigned int b2d[4], b3d[4];
    #pragma unroll
    for (int nt = 0; nt < 4; ++nt) {
        b2d[nt] = (q == 0) ? (unsigned)f2bf(b2[nt * 16 + m16]) : 0u;
        b3d[nt] = (q == 0) ? (unsigned)f2bf(b3[nt * 16 + m16]) : 0u;
    }

    int T = E >> 5;
    for (int t = blockIdx.x * 4 + wid; t < T; t += gridDim.x * 4) {
        int p0 = t * 32;
        int sp0 = p0 + ((m16 >> 2) << 3) + (m16 & 3);
        int sp1 = sp0 + 4;
        int s0 = ssrc[sp0], s1 = ssrc[sp1];
        int pb = p0 + (q << 3);
        int dseq[8];
        #pragma unroll
        for (int j = 0; j < 8; ++j) dseq[j] = sdst[pb + j];

        FU Lb[2]; uint2 ep[2];
        Lb[0].v = *(const short8*)(a_row + (size_t)s0 * 16 + q * 8);
        Lb[1].v = *(const short8*)(a_row + (size_t)s1 * 16 + q * 8);
        ep[0] = *(const uint2*)(spad + (size_t)sp0 * 4);
        ep[1] = *(const uint2*)(spad + (size_t)sp1 * 4);
        #pragma unroll
        for (int mt = 0; mt < 2; ++mt) {
            FU f = Lb[mt];
            f.d[0] = q < 2 ? f.d[0] : (q == 2 ? ep[mt].x : 0u);
            f.d[1] = q < 2 ? f.d[1] : (q == 2 ? ep[mt].y : 0u);
            f.d[2] = q < 2 ? f.d[2] : 0u;
            f.d[3] = q < 2 ? f.d[3] : 0u;
            Lb[mt] = f;
        }

        f32x4 acc1[2][4];
        #pragma unroll
        for (int mt = 0; mt < 2; ++mt)
            #pragma unroll
            for (int nt = 0; nt < 4; ++nt) acc1[mt][nt] = (f32x4){0.f, 0.f, 0.f, 0.f};
        #pragma unroll
        for (int nt = 0; nt < 4; ++nt) {
            short8 wf = *(const short8*)(B1 + (nt * 64 + lane) * 8);
            acc1[0][nt] = MFMA(Lb[0].v, wf, acc1[0][nt]);
            acc1[1][nt] = MFMA(Lb[1].v, wf, acc1[1][nt]);
        }

        f32x4 a3[2][4];
        #pragma unroll
        for (int mt = 0; mt < 2; ++mt) {
            ZTRANS(Zw, acc1[mt])
            FU A2[2];
            A2[0].v = *(const short8*)(Zw + m16 * 72 + 0 * 32 + q * 8);
            A2[1].v = *(const short8*)(Zw + m16 * 72 + 1 * 32 + q * 8);

            f32x4 a2[4];
            #pragma unroll
            for (int nt = 0; nt < 4; ++nt) {
                a2[nt] = (f32x4){0.f, 0.f, 0.f, 0.f};
                short8 w0 = *(const short8*)(B2 + ((0 * 4 + nt) * 64 + lane) * 8);
                short8 w1f = *(const short8*)(B2 + ((1 * 4 + nt) * 64 + lane) * 8);
                a2[nt] = MFMA(A2[0].v, w0, a2[nt]);
                a2[nt] = MFMA(A2[1].v, w1f, a2[nt]);
                FU bf; bf.d[0] = b2d[nt]; bf.d[1] = 0; bf.d[2] = 0; bf.d[3] = 0;
                a2[nt] = MFMA(onesf.v, bf.v, a2[nt]);
            }

            ZTRANS(Zw, a2)
            FU A3[2];
            A3[0].v = *(const short8*)(Zw + m16 * 72 + 0 * 32 + q * 8);
            A3[1].v = *(const short8*)(Zw + m16 * 72 + 1 * 32 + q * 8);

            #pragma unroll
            for (int nt = 0; nt < 4; ++nt) {
                a3[mt][nt] = (f32x4){0.f, 0.f, 0.f, 0.f};
                short8 w0 = *(const short8*)(B3 + ((0 * 4 + nt) * 64 + lane) * 8);
                short8 w1f = *(const short8*)(B3 + ((1 * 4 + nt) * 64 + lane) * 8);
                a3[mt][nt] = MFMA(A3[0].v, w0, a3[mt][nt]);
                a3[mt][nt] = MFMA(A3[1].v, w1f, a3[mt][nt]);
                FU bf; bf.d[0] = b3d[nt]; bf.d[1] = 0; bf.d[2] = 0; bf.d[3] = 0;
                a3[mt][nt] = MFMA(onesf.v, bf.v, a3[mt][nt]);
            }
        }

        bool eq[7];
        #pragma unroll
        for (int j = 0; j < 7; ++j) eq[j] = (dseq[j] == dseq[j + 1]);
        #pragma unroll
        for (int nt = 0; nt < 4; ++nt) {
            float v[8];
            #pragma unroll
            for (int mt = 0; mt < 2; ++mt)
                #pragma unroll
                for (int r = 0; r < 4; ++r) v[mt * 4 + r] = a3[mt][nt][r];
            #pragma unroll
            for (int j = 0; j < 7; ++j) {
                if (eq[j]) v[j + 1] += v[j];
                else unsafeAtomicAdd(&sum_u[(size_t)dseq[j] * 64 + nt * 16 + m16], v[j]);
            }
            unsafeAtomicAdd(&sum_u[(size_t)dseq[7] * 64 + nt * 16 + m16], v[7]);
        }
    }
}

// ---------------------------------------------------------------------------
// prep2: u_row[n][224]; deg from cnt_s (int)
// ---------------------------------------------------------------------------
__global__ __launch_bounds__(256) void prep2(
    const float* __restrict__ ps, const float* __restrict__ h,
    const float* __restrict__ x,
    const float* __restrict__ su, const float* __restrict__ sx,
    const int* __restrict__ cnt_s, unsigned short* __restrict__ u_row, int NS)
{
    int total = NS * 224;
    for (int i = blockIdx.x * 256 + threadIdx.x; i < total; i += gridDim.x * 256) {
        int n = i / 224, k = i - n * 224;
        float v;
        if (k < 2)        v = ps[n * 2 + k];
        else if (k < 66)  v = h[n * 64 + k - 2];
        else if (k < 130) v = su[n * 64 + k - 66];
        else if (k < 194) v = sx[n * 64 + k - 130] * (1.0f / fmaxf((float)cnt_s[n], 1.0f));
        else if (k < 202) v = x[n * 8 + k - 194];
        else if (k == 207) v = 1.0f;
        else              v = 0.f;
        u_row[i] = f2bf(v);
    }
}

// ---------------------------------------------------------------------------
// upd: K=224 from u_row, 16 nodes/wave, row-contiguous store.
// ---------------------------------------------------------------------------
__global__ __launch_bounds__(256) void upd_mfma(
    const unsigned short* __restrict__ u_row,
    const float* __restrict__ w1, const float* __restrict__ b1,
    const float* __restrict__ w2, const float* __restrict__ b2,
    const float* __restrict__ w3, const float* __restrict__ b3,
    float* __restrict__ out, int NS)
{
    __shared__ __align__(16) unsigned short B1[7 * 4 * 64 * 8];
    __shared__ __align__(16) unsigned short B2[2 * 4 * 64 * 8];
    __shared__ __align__(16) unsigned short B3[2 * 4 * 64 * 8];
    __shared__ __align__(16) unsigned short Z[4][16 * 72];

    int tid = threadIdx.x;
    build_frags(w1, b1, B1, 7, tid, [](int k) -> int {
        if (k < 202)  return k;
        if (k == 207) return -1;
        return -2; });
    build_frags(w2, b2, B2, 2, tid, PERM_KM);
    build_frags(w3, b3, B3, 2, tid, PERM_KM);
    __syncthreads();

    int wid = tid >> 6, lane = tid & 63, m16 = lane & 15, q = lane >> 4;
    unsigned short* Zw = Z[wid];

    FU onesf; onesf.d[0] = (q == 0) ? 0x3F80u : 0u; onesf.d[1] = 0; onesf.d[2] = 0; onesf.d[3] = 0;
    unsigned int b2d[4], b3d[4];
    #pragma unroll
    for (int nt = 0; nt < 4; ++nt) {
        b2d[nt] = (q == 0) ? (unsigned)f2bf(b2[nt * 16 + m16]) : 0u;
        b3d[nt] = (q == 0) ? (unsigned)f2bf(b3[nt * 16 + m16]) : 0u;
    }

    int T = NS >> 4;
    for (int t = blockIdx.x * 4 + wid; t < T; t += gridDim.x * 4) {
        int n0 = t * 16;
        const unsigned short* row = u_row + (size_t)(n0 + m16) * 224;

        f32x4 acc1[4];
        #pragma unroll
        for (int nt = 0; nt < 4; ++nt) acc1[nt] = (f32x4){0.f, 0.f, 0.f, 0.f};
        #pragma unroll
        for (int c = 0; c < 7; ++c) {
            short8 afrag = *(const short8*)(row + c * 32 + q * 8);
            #pragma unroll
            for (int nt = 0; nt < 4; ++nt) {
                short8 wf = *(const short8*)(B1 + ((c * 4 + nt) * 64 + lane) * 8);
                acc1[nt] = MFMA(afrag, wf, acc1[nt]);
            }
        }

        ZTRANS(Zw, acc1)
        FU A2[2];
        A2[0].v = *(const short8*)(Zw + m16 * 72 + 0 * 32 + q * 8);
        A2[1].v = *(const short8*)(Zw + m16 * 72 + 1 * 32 + q * 8);

        f32x4 a2[4];
        #pragma unroll
        for (int nt = 0; nt < 4; ++nt) {
            a2[nt] = (f32x4){0.f, 0.f, 0.f, 0.f};
            short8 w0 = *(const short8*)(B2 + ((0 * 4 + nt) * 64 + lane) * 8);
            short8 w1f = *(const short8*)(B2 + ((1 * 4 + nt) * 64 + lane) * 8);
            a2[nt] = MFMA(A2[0].v, w0, a2[nt]);
            a2[nt] = MFMA(A2[1].v, w1f, a2[nt]);
            FU bf; bf.d[0] = b2d[nt]; bf.d[1] = 0; bf.d[2] = 0; bf.d[3] = 0;
            a2[nt] = MFMA(onesf.v, bf.v, a2[nt]);
        }

        ZTRANS(Zw, a2)
        FU A3[2];
        A3[0].v = *(const short8*)(Zw + m16 * 72 + 0 * 32 + q * 8);
        A3[1].v = *(const short8*)(Zw + m16 * 72 + 1 * 32 + q * 8);

        f32x4 a3[4];
        #pragma unroll
        for (int nt = 0; nt < 4; ++nt) {
            a3[nt] = (f32x4){0.f, 0.f, 0.f, 0.f};
            short8 w0 = *(const short8*)(B3 + ((0 * 4 + nt) * 64 + lane) * 8);
            short8 w1f = *(const short8*)(B3 + ((1 * 4 + nt) * 64 + lane) * 8);
            a3[nt] = MFMA(A3[0].v, w0, a3[nt]);
            a3[nt] = MFMA(A3[1].v, w1f, a3[nt]);
            FU bf; bf.d[0] = b3d[nt]; bf.d[1] = 0; bf.d[2] = 0; bf.d[3] = 0;
            a3[nt] = MFMA(onesf.v, bf.v, a3[nt]);
        }

        #pragma unroll
        for (int nt = 0; nt < 4; ++nt)
            #pragma unroll
            for (int r = 0; r < 4; ++r)
                out[(size_t)(n0 + (q << 2) + r) * 64 + nt * 16 + m16] = a3[nt][r];
    }
}

extern "C" void kernel_launch(void* const* d_in, const int* in_sizes, int n_in,
                              void* d_out, int out_size, void* d_ws, size_t ws_size,
                              hipStream_t stream) {
    const float* pos_state  = (const float*)d_in[0];
    const float* pos_action = (const float*)d_in[1];
    const float* h          = (const float*)d_in[2];
    const float* x          = (const float*)d_in[3];
    const float* u          = (const float*)d_in[4];
    const int*   a2s_src    = (const int*)d_in[5];
    const int*   a2s_dst    = (const int*)d_in[6];
    const float* a2s_dis    = (const float*)d_in[7];
    const int*   s2s_src    = (const int*)d_in[8];
    const int*   s2s_dst    = (const int*)d_in[9];
    const float* s2s_dis    = (const float*)d_in[10];
    const float* u2h_w1 = (const float*)d_in[11]; const float* u2h_b1 = (const float*)d_in[12];
    const float* u2h_w2 = (const float*)d_in[13]; const float* u2h_b2 = (const float*)d_in[14];
    const float* u2h_w3 = (const float*)d_in[15]; const float* u2h_b3 = (const float*)d_in[16];
    const float* x2h_w1 = (const float*)d_in[17]; const float* x2h_b1 = (const float*)d_in[18];
    const float* x2h_w2 = (const float*)d_in[19]; const float* x2h_b2 = (const float*)d_in[20];
    const float* x2h_w3 = (const float*)d_in[21]; const float* x2h_b3 = (const float*)d_in[22];
    const float* upd_w1 = (const float*)d_in[23]; const float* upd_b1 = (const float*)d_in[24];
    const float* upd_w2 = (const float*)d_in[25]; const float* upd_b2 = (const float*)d_in[26];
    const float* upd_w3 = (const float*)d_in[27]; const float* upd_b3 = (const float*)d_in[28];

    int NS = in_sizes[0] / 2;
    int NA = in_sizes[1] / 2;
    int EA = in_sizes[5];
    int ES = in_sizes[8];

    char* p = (char*)d_ws;
    int*   cnt_s = (int*)p;            p += (size_t)NS * 4;
    int*   cnt_a = (int*)p;            p += (size_t)NS * 4;
    float* sum_u = (float*)p;          p += (size_t)NS * 64 * 4;
    float* sum_x = (float*)p;          p += (size_t)NS * 64 * 4;
    size_t zbytes = (size_t)(p - (char*)d_ws);   // memset region ends here
    unsigned short* u_row = (unsigned short*)p;  // aliases everything below (used after edge kernels)
    int*   off_s  = (int*)p;           p += (size_t)NS * 4;
    int*   off_a  = (int*)p;           p += (size_t)NS * 4;
    int*   rank_s = (int*)p;           p += (size_t)ES * 4;
    int*   rank_a = (int*)p;           p += (size_t)EA * 4;
    unsigned short* e_pad_s = (unsigned short*)p; p += (size_t)ES * 8;
    unsigned short* e_pad_a = (unsigned short*)p; p += (size_t)EA * 8;
    // ---- nothing above this line (except u_row alias region start) survives past edge kernels
    // u_row needs NS*224*2 = 22.4 MB; region above = 0.4+6+12 = 18.4 MB -> extend alias window:
    int*   ssrc_s = (int*)p;           p += (size_t)ES * 4;
    int*   sdst_s = (int*)p;           p += (size_t)ES * 4;
    unsigned short* spad_s = (unsigned short*)p; p += (size_t)ES * 8;
    int*   ssrc_a = (int*)p;           p += (size_t)EA * 4;
    int*   sdst_a = (int*)p;           p += (size_t)EA * 4;
    unsigned short* spad_a = (unsigned short*)p; p += (size_t)EA * 8;
    unsigned short* s_row  = (unsigned short*)p; p += (size_t)NS * 80 * 2;
    unsigned short* a_row  = (unsigned short*)p; p += (size_t)NA * 16 * 2;
    (void)ws_size;

    hipMemsetAsync(d_ws, 0, zbytes, stream);

    prep1<<<2048, 256, 0, stream>>>(pos_state, pos_action, h, x, u,
                                    s2s_dst, s2s_dis, a2s_dst, a2s_dis,
                                    s_row, a_row, e_pad_s, e_pad_a,
                                    cnt_s, rank_s, cnt_a, rank_a,
                                    NS, NA, ES, EA);
    scan2<<<1, 1024, 0, stream>>>(cnt_s, off_s, cnt_a, off_a, NS);
    scatter_sort<<<1024, 256, 0, stream>>>(s2s_src, s2s_dst, rank_s, off_s,
                                           e_pad_s, ssrc_s, sdst_s, spad_s, ES);
    scatter_sort<<<1024, 256, 0, stream>>>(a2s_src, a2s_dst, rank_a, off_a,
                                           e_pad_a, ssrc_a, sdst_a, spad_a, EA);
    a2s_mfma<<<1024, 256, 0, stream>>>(a_row, ssrc_a, sdst_a, spad_a,
                                       u2h_w1, u2h_b1, u2h_w2, u2h_b2, u2h_w3, u2h_b3,
                                       sum_u, EA);
    s2s_mfma<<<1024, 256, 0, stream>>>(s_row, ssrc_s, sdst_s, spad_s,
                                       x2h_w1, x2h_b1, x2h_w2, x2h_b2, x2h_w3, x2h_b3,
                                       sum_x, ES);
    prep2<<<2048, 256, 0, stream>>>(pos_state, h, x, sum_u, sum_x, cnt_s, u_row, NS);
    upd_mfma<<<768, 256, 0, stream>>>(u_row,
                                      upd_w1, upd_b1, upd_w2, upd_b2, upd_w3, upd_b3,
                                      (float*)d_out, NS);
}

// Round 6
// 547.785 us; speedup vs baseline: 1.1975x; 1.1975x over previous
//
#include <hip/hip_runtime.h>
#include <hip/hip_bf16.h>

// R6: R5's dst-sorted segmented-reduction pipeline with the single-block scan
// (154 us, 1-CU latency-bound) replaced by a 3-kernel multi-block scan (~10 us),
// and e_pad construction folded into scatter_sort (prep1 sheds 8MB of traffic).

typedef __attribute__((ext_vector_type(8))) short short8;
typedef __attribute__((ext_vector_type(4))) float f32x4;

#define MFMA(a, b, c) __builtin_amdgcn_mfma_f32_16x16x32_bf16(a, b, c, 0, 0, 0)

union FU { short8 v; unsigned int d[4]; unsigned short us[8]; };

__device__ __forceinline__ unsigned short f2bf(float f) {
    unsigned u = __float_as_uint(f);
    u += 0x7fffu + ((u >> 16) & 1u);   // RNE (data NaN-free)
    return (unsigned short)(u >> 16);
}
__device__ __forceinline__ unsigned int pack2(float a, float b) {
    return (unsigned int)f2bf(a) | ((unsigned int)f2bf(b) << 16);
}
__device__ __forceinline__ float tanh_fast(float xv) {
    float t = __builtin_amdgcn_exp2f(xv * 2.8853900817779268f); // 2*log2(e)
    return 1.0f - 2.0f * __builtin_amdgcn_rcpf(t + 1.0f);
}

template <typename KM>
__device__ void build_frags(const float* __restrict__ w, const float* __restrict__ b,
                            unsigned short* dst, int nchunks, int tid, KM km) {
    int total = nchunks * 4 * 64;
    for (int f = tid; f < total; f += 256) {
        int lv = f & 63, nt = (f >> 6) & 3, c = f >> 8;
        int n = nt * 16 + (lv & 15);
        int kb = c * 32 + ((lv >> 4) << 3);
        unsigned short* o = dst + f * 8;
        #pragma unroll
        for (int j = 0; j < 8; ++j) {
            int sk = km(kb + j);
            float v = (sk >= 0) ? w[sk * 64 + n] : (sk == -1 ? b[n] : 0.f);
            o[j] = f2bf(v);
        }
    }
}

#define PERM_KM [](int k) -> int { return (k >> 2) + 16 * (k & 3); }

// C-layout (lane q,m16 holds row=q*4+r, feat=nt*16+m16) -> Zb[row][kpos],
// kpos = 4*m16 + nt. One b64 write per r; row stride 72 elems.
#define ZTRANS(Zw, accv)                                                       \
    _Pragma("unroll")                                                          \
    for (int r = 0; r < 4; ++r) {                                              \
        uint2 pv;                                                              \
        pv.x = pack2(tanh_fast(accv[0][r]), tanh_fast(accv[1][r]));            \
        pv.y = pack2(tanh_fast(accv[2][r]), tanh_fast(accv[3][r]));            \
        *(uint2*)((Zw) + ((q << 2) + r) * 72 + (m16 << 2)) = pv;               \
    }

// ---------------------------------------------------------------------------
// prep1: bf16 row tables + per-dst counts & ranks (both graphs)
// ---------------------------------------------------------------------------
__global__ __launch_bounds__(256) void prep1(
    const float* __restrict__ ps, const float* __restrict__ pa,
    const float* __restrict__ h, const float* __restrict__ x,
    const float* __restrict__ u,
    const int* __restrict__ s2s_dst, const int* __restrict__ a2s_dst,
    unsigned short* __restrict__ s_row, unsigned short* __restrict__ a_row,
    int* __restrict__ cnt_s, int* __restrict__ rank_s,
    int* __restrict__ cnt_a, int* __restrict__ rank_a,
    int NS, int NA, int ES, int EA)
{
    int R0 = NS * 80, R1 = R0 + NA * 16, R2 = R1 + ES, R3 = R2 + EA;
    for (int i = blockIdx.x * 256 + threadIdx.x; i < R3; i += gridDim.x * 256) {
        if (i < R0) {
            int n = i / 80, k = i - n * 80;
            float v = (k < 2) ? ps[n * 2 + k] : (k < 10) ? x[n * 8 + k - 2]
                    : (k < 74) ? h[n * 64 + k - 10] : 0.f;
            s_row[i] = f2bf(v);
        } else if (i < R1) {
            int j = i - R0; int a = j / 16, k = j - a * 16;
            float v = (k < 2) ? pa[a * 2 + k] : (k < 10) ? u[a * 8 + k - 2] : 0.f;
            a_row[j] = f2bf(v);
        } else if (i < R2) {
            int e = i - R1;
            rank_s[e] = atomicAdd(&cnt_s[s2s_dst[e]], 1);
        } else {
            int e = i - R2;
            rank_a[e] = atomicAdd(&cnt_a[a2s_dst[e]], 1);
        }
    }
}

// ---------------------------------------------------------------------------
// 3-phase multi-block exclusive scan over concatenated [cnt_s | cnt_a] (2*NS).
// off_a values get -ES (sum of cnt_s) so each sorted array starts at 0.
// ---------------------------------------------------------------------------
#define SCAN_CHUNK 1024

__global__ __launch_bounds__(256) void scan_a(const int* __restrict__ cnt,
                                              int* __restrict__ bsum, int N2)
{
    __shared__ int red[256];
    int t = threadIdx.x;
    int base = blockIdx.x * SCAN_CHUNK + t * 4;
    int s = 0;
    #pragma unroll
    for (int j = 0; j < 4; ++j) { int i = base + j; if (i < N2) s += cnt[i]; }
    red[t] = s; __syncthreads();
    for (int d = 128; d > 0; d >>= 1) {
        if (t < d) red[t] += red[t + d];
        __syncthreads();
    }
    if (t == 0) bsum[blockIdx.x] = red[0];
}

__global__ __launch_bounds__(128) void scan_b(int* __restrict__ bsum, int NB)
{
    __shared__ int part[128];
    int t = threadIdx.x;
    int v = (t < NB) ? bsum[t] : 0;
    part[t] = v; __syncthreads();
    for (int d = 1; d < 128; d <<= 1) {
        int w = (t >= d) ? part[t - d] : 0;
        __syncthreads();
        part[t] += w;
        __syncthreads();
    }
    if (t < NB) bsum[t] = part[t] - v;   // exclusive block prefix
}

__global__ __launch_bounds__(256) void scan_c(const int* __restrict__ cnt,
                                              const int* __restrict__ bsum,
                                              int* __restrict__ off,
                                              int N2, int NS, int ES)
{
    __shared__ int part[256];
    int t = threadIdx.x;
    int base = blockIdx.x * SCAN_CHUNK + t * 4;
    int c[4]; int s = 0;
    #pragma unroll
    for (int j = 0; j < 4; ++j) { int i = base + j; c[j] = (i < N2) ? cnt[i] : 0; s += c[j]; }
    part[t] = s; __syncthreads();
    for (int d = 1; d < 256; d <<= 1) {
        int w = (t >= d) ? part[t - d] : 0;
        __syncthreads();
        part[t] += w;
        __syncthreads();
    }
    int run = bsum[blockIdx.x] + part[t] - s;
    #pragma unroll
    for (int j = 0; j < 4; ++j) {
        int i = base + j;
        if (i < N2) off[i] = run - ((i >= NS) ? ES : 0);
        run += c[j];
    }
}

// ---------------------------------------------------------------------------
// scatter_sort: materialize dst-sorted src/dst/pad arrays (plain stores);
// builds the bf16 pad (ps[dst], dis, 1.0) inline.
// ---------------------------------------------------------------------------
__global__ __launch_bounds__(256) void scatter_sort(
    const int* __restrict__ src, const int* __restrict__ dst,
    const int* __restrict__ rank, const int* __restrict__ off,
    const float* __restrict__ dis, const float* __restrict__ ps,
    int* __restrict__ ssrc, int* __restrict__ sdst,
    unsigned short* __restrict__ spad, int E)
{
    for (int i = blockIdx.x * 256 + threadIdx.x; i < E; i += gridDim.x * 256) {
        int d = dst[i];
        int pos = off[d] + rank[i];
        ssrc[pos] = src[i];
        sdst[pos] = d;
        uint2 p;
        p.x = pack2(ps[d * 2], ps[d * 2 + 1]);
        p.y = (unsigned)f2bf(dis[i]) | (0x3F80u << 16);   // dis, 1.0
        *(uint2*)(spad + (size_t)pos * 4) = p;
    }
}

// ---------------------------------------------------------------------------
// s2s: sorted edges, K=96 [s_row(80) | psd,dis,1.0,0...], segmented scatter.
// Row map: lane q's 8 C-rows (both mt tiles) are consecutive sorted edges.
// ---------------------------------------------------------------------------
__global__ __launch_bounds__(256) void s2s_mfma(
    const unsigned short* __restrict__ s_row,
    const int* __restrict__ ssrc, const int* __restrict__ sdst,
    const unsigned short* __restrict__ spad,
    const float* __restrict__ w1, const float* __restrict__ b1,
    const float* __restrict__ w2, const float* __restrict__ b2,
    const float* __restrict__ w3, const float* __restrict__ b3,
    float* __restrict__ sum_x, int E)
{
    __shared__ __align__(16) unsigned short B1[3 * 4 * 64 * 8];
    __shared__ __align__(16) unsigned short B2[2 * 4 * 64 * 8];
    __shared__ __align__(16) unsigned short B3[2 * 4 * 64 * 8];
    __shared__ __align__(16) unsigned short Z[4][16 * 72];

    int tid = threadIdx.x;
    build_frags(w1, b1, B1, 3, tid, [](int k) -> int {
        if (k < 2)   return k;
        if (k < 74)  return k + 3;
        if (k < 80)  return -2;
        if (k < 82)  return k - 78;
        if (k == 82) return 4;
        if (k == 83) return -1;
        return -2; });
    build_frags(w2, b2, B2, 2, tid, PERM_KM);
    build_frags(w3, b3, B3, 2, tid, PERM_KM);
    __syncthreads();

    int wid = tid >> 6, lane = tid & 63, m16 = lane & 15, q = lane >> 4;
    unsigned short* Zw = Z[wid];

    FU onesf; onesf.d[0] = (q == 0) ? 0x3F80u : 0u; onesf.d[1] = 0; onesf.d[2] = 0; onesf.d[3] = 0;
    unsigned int b2d[4], b3d[4];
    #pragma unroll
    for (int nt = 0; nt < 4; ++nt) {
        b2d[nt] = (q == 0) ? (unsigned)f2bf(b2[nt * 16 + m16]) : 0u;
        b3d[nt] = (q == 0) ? (unsigned)f2bf(b3[nt * 16 + m16]) : 0u;
    }

    int T = E >> 5;
    for (int t = blockIdx.x * 4 + wid; t < T; t += gridDim.x * 4) {
        int p0 = t * 32;
        int sp0 = p0 + ((m16 >> 2) << 3) + (m16 & 3);  // mt=0 A row
        int sp1 = sp0 + 4;                              // mt=1 A row
        int s0 = ssrc[sp0], s1 = ssrc[sp1];
        int pb = p0 + (q << 3);
        int dseq[8];
        #pragma unroll
        for (int j = 0; j < 8; ++j) dseq[j] = sdst[pb + j];

        FU Lb[2][3]; uint2 ep[2];
        const unsigned short* rA = s_row + (size_t)s0 * 80;
        const unsigned short* rB = s_row + (size_t)s1 * 80;
        #pragma unroll
        for (int c = 0; c < 3; ++c) {
            Lb[0][c].v = *(const short8*)(rA + c * 32 + q * 8);
            Lb[1][c].v = *(const short8*)(rB + c * 32 + q * 8);
        }
        ep[0] = *(const uint2*)(spad + (size_t)sp0 * 4);
        ep[1] = *(const uint2*)(spad + (size_t)sp1 * 4);
        #pragma unroll
        for (int mt = 0; mt < 2; ++mt) {            // chunk 2: q2=pad, q3=0
            FU f = Lb[mt][2];
            f.d[0] = q < 2 ? f.d[0] : (q == 2 ? ep[mt].x : 0u);
            f.d[1] = q < 2 ? f.d[1] : (q == 2 ? ep[mt].y : 0u);
            f.d[2] = q < 2 ? f.d[2] : 0u;
            f.d[3] = q < 2 ? f.d[3] : 0u;
            Lb[mt][2] = f;
        }

        f32x4 acc1[2][4];
        #pragma unroll
        for (int mt = 0; mt < 2; ++mt)
            #pragma unroll
            for (int nt = 0; nt < 4; ++nt) acc1[mt][nt] = (f32x4){0.f, 0.f, 0.f, 0.f};
        #pragma unroll
        for (int c = 0; c < 3; ++c)
            #pragma unroll
            for (int nt = 0; nt < 4; ++nt) {
                short8 wf = *(const short8*)(B1 + ((c * 4 + nt) * 64 + lane) * 8);
                acc1[0][nt] = MFMA(Lb[0][c].v, wf, acc1[0][nt]);
                acc1[1][nt] = MFMA(Lb[1][c].v, wf, acc1[1][nt]);
            }

        f32x4 a3[2][4];
        #pragma unroll
        for (int mt = 0; mt < 2; ++mt) {
            ZTRANS(Zw, acc1[mt])
            FU A2[2];
            A2[0].v = *(const short8*)(Zw + m16 * 72 + 0 * 32 + q * 8);
            A2[1].v = *(const short8*)(Zw + m16 * 72 + 1 * 32 + q * 8);

            f32x4 a2[4];
            #pragma unroll
            for (int nt = 0; nt < 4; ++nt) {
                a2[nt] = (f32x4){0.f, 0.f, 0.f, 0.f};
                short8 w0 = *(const short8*)(B2 + ((0 * 4 + nt) * 64 + lane) * 8);
                short8 w1f = *(const short8*)(B2 + ((1 * 4 + nt) * 64 + lane) * 8);
                a2[nt] = MFMA(A2[0].v, w0, a2[nt]);
                a2[nt] = MFMA(A2[1].v, w1f, a2[nt]);
                FU bf; bf.d[0] = b2d[nt]; bf.d[1] = 0; bf.d[2] = 0; bf.d[3] = 0;
                a2[nt] = MFMA(onesf.v, bf.v, a2[nt]);
            }

            ZTRANS(Zw, a2)
            FU A3[2];
            A3[0].v = *(const short8*)(Zw + m16 * 72 + 0 * 32 + q * 8);
            A3[1].v = *(const short8*)(Zw + m16 * 72 + 1 * 32 + q * 8);

            #pragma unroll
            for (int nt = 0; nt < 4; ++nt) {
                a3[mt][nt] = (f32x4){0.f, 0.f, 0.f, 0.f};
                short8 w0 = *(const short8*)(B3 + ((0 * 4 + nt) * 64 + lane) * 8);
                short8 w1f = *(const short8*)(B3 + ((1 * 4 + nt) * 64 + lane) * 8);
                a3[mt][nt] = MFMA(A3[0].v, w0, a3[mt][nt]);
                a3[mt][nt] = MFMA(A3[1].v, w1f, a3[mt][nt]);
                FU bf; bf.d[0] = b3d[nt]; bf.d[1] = 0; bf.d[2] = 0; bf.d[3] = 0;
                a3[mt][nt] = MFMA(onesf.v, bf.v, a3[mt][nt]);
            }
        }

        // segmented emit over 8 consecutive sorted edges (j = 4*mt + r)
        bool eq[7];
        #pragma unroll
        for (int j = 0; j < 7; ++j) eq[j] = (dseq[j] == dseq[j + 1]);
        #pragma unroll
        for (int nt = 0; nt < 4; ++nt) {
            float v[8];
            #pragma unroll
            for (int mt = 0; mt < 2; ++mt)
                #pragma unroll
                for (int r = 0; r < 4; ++r) v[mt * 4 + r] = a3[mt][nt][r];
            #pragma unroll
            for (int j = 0; j < 7; ++j) {
                if (eq[j]) v[j + 1] += v[j];
                else unsafeAtomicAdd(&sum_x[(size_t)dseq[j] * 64 + nt * 16 + m16], v[j]);
            }
            unsafeAtomicAdd(&sum_x[(size_t)dseq[7] * 64 + nt * 16 + m16], v[7]);
        }
    }
}

// ---------------------------------------------------------------------------
// a2s: sorted edges, K=32 [a_row(16) | psd,dis,1.0,0...], segmented scatter.
// ---------------------------------------------------------------------------
__global__ __launch_bounds__(256) void a2s_mfma(
    const unsigned short* __restrict__ a_row,
    const int* __restrict__ ssrc, const int* __restrict__ sdst,
    const unsigned short* __restrict__ spad,
    const float* __restrict__ w1, const float* __restrict__ b1,
    const float* __restrict__ w2, const float* __restrict__ b2,
    const float* __restrict__ w3, const float* __restrict__ b3,
    float* __restrict__ sum_u, int E)
{
    __shared__ __align__(16) unsigned short B1[1 * 4 * 64 * 8];
    __shared__ __align__(16) unsigned short B2[2 * 4 * 64 * 8];
    __shared__ __align__(16) unsigned short B3[2 * 4 * 64 * 8];
    __shared__ __align__(16) unsigned short Z[4][16 * 72];

    int tid = threadIdx.x;
    build_frags(w1, b1, B1, 1, tid, [](int k) -> int {
        if (k < 2)   return k;
        if (k < 10)  return k + 3;
        if (k < 16)  return -2;
        if (k < 18)  return k - 14;
        if (k == 18) return 4;
        if (k == 19) return -1;
        return -2; });
    build_frags(w2, b2, B2, 2, tid, PERM_KM);
    build_frags(w3, b3, B3, 2, tid, PERM_KM);
    __syncthreads();

    int wid = tid >> 6, lane = tid & 63, m16 = lane & 15, q = lane >> 4;
    unsigned short* Zw = Z[wid];

    FU onesf; onesf.d[0] = (q == 0) ? 0x3F80u : 0u; onesf.d[1] = 0; onesf.d[2] = 0; onesf.d[3] = 0;
    unsigned int b2d[4], b3d[4];
    #pragma unroll
    for (int nt = 0; nt < 4; ++nt) {
        b2d[nt] = (q == 0) ? (unsigned)f2bf(b2[nt * 16 + m16]) : 0u;
        b3d[nt] = (q == 0) ? (unsigned)f2bf(b3[nt * 16 + m16]) : 0u;
    }

    int T = E >> 5;
    for (int t = blockIdx.x * 4 + wid; t < T; t += gridDim.x * 4) {
        int p0 = t * 32;
        int sp0 = p0 + ((m16 >> 2) << 3) + (m16 & 3);
        int sp1 = sp0 + 4;
        int s0 = ssrc[sp0], s1 = ssrc[sp1];
        int pb = p0 + (q << 3);
        int dseq[8];
        #pragma unroll
        for (int j = 0; j < 8; ++j) dseq[j] = sdst[pb + j];

        FU Lb[2]; uint2 ep[2];
        Lb[0].v = *(const short8*)(a_row + (size_t)s0 * 16 + q * 8);
        Lb[1].v = *(const short8*)(a_row + (size_t)s1 * 16 + q * 8);
        ep[0] = *(const uint2*)(spad + (size_t)sp0 * 4);
        ep[1] = *(const uint2*)(spad + (size_t)sp1 * 4);
        #pragma unroll
        for (int mt = 0; mt < 2; ++mt) {
            FU f = Lb[mt];
            f.d[0] = q < 2 ? f.d[0] : (q == 2 ? ep[mt].x : 0u);
            f.d[1] = q < 2 ? f.d[1] : (q == 2 ? ep[mt].y : 0u);
            f.d[2] = q < 2 ? f.d[2] : 0u;
            f.d[3] = q < 2 ? f.d[3] : 0u;
            Lb[mt] = f;
        }

        f32x4 acc1[2][4];
        #pragma unroll
        for (int mt = 0; mt < 2; ++mt)
            #pragma unroll
            for (int nt = 0; nt < 4; ++nt) acc1[mt][nt] = (f32x4){0.f, 0.f, 0.f, 0.f};
        #pragma unroll
        for (int nt = 0; nt < 4; ++nt) {
            short8 wf = *(const short8*)(B1 + (nt * 64 + lane) * 8);
            acc1[0][nt] = MFMA(Lb[0].v, wf, acc1[0][nt]);
            acc1[1][nt] = MFMA(Lb[1].v, wf, acc1[1][nt]);
        }

        f32x4 a3[2][4];
        #pragma unroll
        for (int mt = 0; mt < 2; ++mt) {
            ZTRANS(Zw, acc1[mt])
            FU A2[2];
            A2[0].v = *(const short8*)(Zw + m16 * 72 + 0 * 32 + q * 8);
            A2[1].v = *(const short8*)(Zw + m16 * 72 + 1 * 32 + q * 8);

            f32x4 a2[4];
            #pragma unroll
            for (int nt = 0; nt < 4; ++nt) {
                a2[nt] = (f32x4){0.f, 0.f, 0.f, 0.f};
                short8 w0 = *(const short8*)(B2 + ((0 * 4 + nt) * 64 + lane) * 8);
                short8 w1f = *(const short8*)(B2 + ((1 * 4 + nt) * 64 + lane) * 8);
                a2[nt] = MFMA(A2[0].v, w0, a2[nt]);
                a2[nt] = MFMA(A2[1].v, w1f, a2[nt]);
                FU bf; bf.d[0] = b2d[nt]; bf.d[1] = 0; bf.d[2] = 0; bf.d[3] = 0;
                a2[nt] = MFMA(onesf.v, bf.v, a2[nt]);
            }

            ZTRANS(Zw, a2)
            FU A3[2];
            A3[0].v = *(const short8*)(Zw + m16 * 72 + 0 * 32 + q * 8);
            A3[1].v = *(const short8*)(Zw + m16 * 72 + 1 * 32 + q * 8);

            #pragma unroll
            for (int nt = 0; nt < 4; ++nt) {
                a3[mt][nt] = (f32x4){0.f, 0.f, 0.f, 0.f};
                short8 w0 = *(const short8*)(B3 + ((0 * 4 + nt) * 64 + lane) * 8);
                short8 w1f = *(const short8*)(B3 + ((1 * 4 + nt) * 64 + lane) * 8);
                a3[mt][nt] = MFMA(A3[0].v, w0, a3[mt][nt]);
                a3[mt][nt] = MFMA(A3[1].v, w1f, a3[mt][nt]);
                FU bf; bf.d[0] = b3d[nt]; bf.d[1] = 0; bf.d[2] = 0; bf.d[3] = 0;
                a3[mt][nt] = MFMA(onesf.v, bf.v, a3[mt][nt]);
            }
        }

        bool eq[7];
        #pragma unroll
        for (int j = 0; j < 7; ++j) eq[j] = (dseq[j] == dseq[j + 1]);
        #pragma unroll
        for (int nt = 0; nt < 4; ++nt) {
            float v[8];
            #pragma unroll
            for (int mt = 0; mt < 2; ++mt)
                #pragma unroll
                for (int r = 0; r < 4; ++r) v[mt * 4 + r] = a3[mt][nt][r];
            #pragma unroll
            for (int j = 0; j < 7; ++j) {
                if (eq[j]) v[j + 1] += v[j];
                else unsafeAtomicAdd(&sum_u[(size_t)dseq[j] * 64 + nt * 16 + m16], v[j]);
            }
            unsafeAtomicAdd(&sum_u[(size_t)dseq[7] * 64 + nt * 16 + m16], v[7]);
        }
    }
}

// ---------------------------------------------------------------------------
// prep2: u_row[n][224]; deg from cnt_s (int)
// ---------------------------------------------------------------------------
__global__ __launch_bounds__(256) void prep2(
    const float* __restrict__ ps, const float* __restrict__ h,
    const float* __restrict__ x,
    const float* __restrict__ su, const float* __restrict__ sx,
    const int* __restrict__ cnt_s, unsigned short* __restrict__ u_row, int NS)
{
    int total = NS * 224;
    for (int i = blockIdx.x * 256 + threadIdx.x; i < total; i += gridDim.x * 256) {
        int n = i / 224, k = i - n * 224;
        float v;
        if (k < 2)        v = ps[n * 2 + k];
        else if (k < 66)  v = h[n * 64 + k - 2];
        else if (k < 130) v = su[n * 64 + k - 66];
        else if (k < 194) v = sx[n * 64 + k - 130] * (1.0f / fmaxf((float)cnt_s[n], 1.0f));
        else if (k < 202) v = x[n * 8 + k - 194];
        else if (k == 207) v = 1.0f;
        else              v = 0.f;
        u_row[i] = f2bf(v);
    }
}

// ---------------------------------------------------------------------------
// upd: K=224 from u_row, 16 nodes/wave, row-contiguous store.
// ---------------------------------------------------------------------------
__global__ __launch_bounds__(256) void upd_mfma(
    const unsigned short* __restrict__ u_row,
    const float* __restrict__ w1, const float* __restrict__ b1,
    const float* __restrict__ w2, const float* __restrict__ b2,
    const float* __restrict__ w3, const float* __restrict__ b3,
    float* __restrict__ out, int NS)
{
    __shared__ __align__(16) unsigned short B1[7 * 4 * 64 * 8];
    __shared__ __align__(16) unsigned short B2[2 * 4 * 64 * 8];
    __shared__ __align__(16) unsigned short B3[2 * 4 * 64 * 8];
    __shared__ __align__(16) unsigned short Z[4][16 * 72];

    int tid = threadIdx.x;
    build_frags(w1, b1, B1, 7, tid, [](int k) -> int {
        if (k < 202)  return k;
        if (k == 207) return -1;
        return -2; });
    build_frags(w2, b2, B2, 2, tid, PERM_KM);
    build_frags(w3, b3, B3, 2, tid, PERM_KM);
    __syncthreads();

    int wid = tid >> 6, lane = tid & 63, m16 = lane & 15, q = lane >> 4;
    unsigned short* Zw = Z[wid];

    FU onesf; onesf.d[0] = (q == 0) ? 0x3F80u : 0u; onesf.d[1] = 0; onesf.d[2] = 0; onesf.d[3] = 0;
    unsigned int b2d[4], b3d[4];
    #pragma unroll
    for (int nt = 0; nt < 4; ++nt) {
        b2d[nt] = (q == 0) ? (unsigned)f2bf(b2[nt * 16 + m16]) : 0u;
        b3d[nt] = (q == 0) ? (unsigned)f2bf(b3[nt * 16 + m16]) : 0u;
    }

    int T = NS >> 4;
    for (int t = blockIdx.x * 4 + wid; t < T; t += gridDim.x * 4) {
        int n0 = t * 16;
        const unsigned short* row = u_row + (size_t)(n0 + m16) * 224;

        f32x4 acc1[4];
        #pragma unroll
        for (int nt = 0; nt < 4; ++nt) acc1[nt] = (f32x4){0.f, 0.f, 0.f, 0.f};
        #pragma unroll
        for (int c = 0; c < 7; ++c) {
            short8 afrag = *(const short8*)(row + c * 32 + q * 8);
            #pragma unroll
            for (int nt = 0; nt < 4; ++nt) {
                short8 wf = *(const short8*)(B1 + ((c * 4 + nt) * 64 + lane) * 8);
                acc1[nt] = MFMA(afrag, wf, acc1[nt]);
            }
        }

        ZTRANS(Zw, acc1)
        FU A2[2];
        A2[0].v = *(const short8*)(Zw + m16 * 72 + 0 * 32 + q * 8);
        A2[1].v = *(const short8*)(Zw + m16 * 72 + 1 * 32 + q * 8);

        f32x4 a2[4];
        #pragma unroll
        for (int nt = 0; nt < 4; ++nt) {
            a2[nt] = (f32x4){0.f, 0.f, 0.f, 0.f};
            short8 w0 = *(const short8*)(B2 + ((0 * 4 + nt) * 64 + lane) * 8);
            short8 w1f = *(const short8*)(B2 + ((1 * 4 + nt) * 64 + lane) * 8);
            a2[nt] = MFMA(A2[0].v, w0, a2[nt]);
            a2[nt] = MFMA(A2[1].v, w1f, a2[nt]);
            FU bf; bf.d[0] = b2d[nt]; bf.d[1] = 0; bf.d[2] = 0; bf.d[3] = 0;
            a2[nt] = MFMA(onesf.v, bf.v, a2[nt]);
        }

        ZTRANS(Zw, a2)
        FU A3[2];
        A3[0].v = *(const short8*)(Zw + m16 * 72 + 0 * 32 + q * 8);
        A3[1].v = *(const short8*)(Zw + m16 * 72 + 1 * 32 + q * 8);

        f32x4 a3[4];
        #pragma unroll
        for (int nt = 0; nt < 4; ++nt) {
            a3[nt] = (f32x4){0.f, 0.f, 0.f, 0.f};
            short8 w0 = *(const short8*)(B3 + ((0 * 4 + nt) * 64 + lane) * 8);
            short8 w1f = *(const short8*)(B3 + ((1 * 4 + nt) * 64 + lane) * 8);
            a3[nt] = MFMA(A3[0].v, w0, a3[nt]);
            a3[nt] = MFMA(A3[1].v, w1f, a3[nt]);
            FU bf; bf.d[0] = b3d[nt]; bf.d[1] = 0; bf.d[2] = 0; bf.d[3] = 0;
            a3[nt] = MFMA(onesf.v, bf.v, a3[nt]);
        }

        #pragma unroll
        for (int nt = 0; nt < 4; ++nt)
            #pragma unroll
            for (int r = 0; r < 4; ++r)
                out[(size_t)(n0 + (q << 2) + r) * 64 + nt * 16 + m16] = a3[nt][r];
    }
}

extern "C" void kernel_launch(void* const* d_in, const int* in_sizes, int n_in,
                              void* d_out, int out_size, void* d_ws, size_t ws_size,
                              hipStream_t stream) {
    const float* pos_state  = (const float*)d_in[0];
    const float* pos_action = (const float*)d_in[1];
    const float* h          = (const float*)d_in[2];
    const float* x          = (const float*)d_in[3];
    const float* u          = (const float*)d_in[4];
    const int*   a2s_src    = (const int*)d_in[5];
    const int*   a2s_dst    = (const int*)d_in[6];
    const float* a2s_dis    = (const float*)d_in[7];
    const int*   s2s_src    = (const int*)d_in[8];
    const int*   s2s_dst    = (const int*)d_in[9];
    const float* s2s_dis    = (const float*)d_in[10];
    const float* u2h_w1 = (const float*)d_in[11]; const float* u2h_b1 = (const float*)d_in[12];
    const float* u2h_w2 = (const float*)d_in[13]; const float* u2h_b2 = (const float*)d_in[14];
    const float* u2h_w3 = (const float*)d_in[15]; const float* u2h_b3 = (const float*)d_in[16];
    const float* x2h_w1 = (const float*)d_in[17]; const float* x2h_b1 = (const float*)d_in[18];
    const float* x2h_w2 = (const float*)d_in[19]; const float* x2h_b2 = (const float*)d_in[20];
    const float* x2h_w3 = (const float*)d_in[21]; const float* x2h_b3 = (const float*)d_in[22];
    const float* upd_w1 = (const float*)d_in[23]; const float* upd_b1 = (const float*)d_in[24];
    const float* upd_w2 = (const float*)d_in[25]; const float* upd_b2 = (const float*)d_in[26];
    const float* upd_w3 = (const float*)d_in[27]; const float* upd_b3 = (const float*)d_in[28];

    int NS = in_sizes[0] / 2;
    int NA = in_sizes[1] / 2;
    int EA = in_sizes[5];
    int ES = in_sizes[8];
    int N2 = 2 * NS;
    int NB = (N2 + SCAN_CHUNK - 1) / SCAN_CHUNK;

    char* p = (char*)d_ws;
    int*   cnt2  = (int*)p;            p += (size_t)N2 * 4;       // cnt_s | cnt_a
    float* sum_u = (float*)p;          p += (size_t)NS * 64 * 4;
    float* sum_x = (float*)p;          p += (size_t)NS * 64 * 4;
    size_t zbytes = (size_t)(p - (char*)d_ws);   // memset region ends here
    unsigned short* u_row = (unsigned short*)p;  // alias window (22.4 MB), dead by prep2
    int*   off2   = (int*)p;           p += (size_t)N2 * 4;       // off_s | off_a
    int*   rank_s = (int*)p;           p += (size_t)ES * 4;
    int*   rank_a = (int*)p;           p += (size_t)EA * 4;
    int*   ssrc_s = (int*)p;           p += (size_t)ES * 4;
    int*   sdst_s = (int*)p;           p += (size_t)ES * 4;
    unsigned short* spad_s = (unsigned short*)p; p += (size_t)ES * 8;
    // u_row (NS*224*2 = 22.4 MB) ends exactly here; below survives into prep2 era
    int*   ssrc_a = (int*)p;           p += (size_t)EA * 4;
    int*   sdst_a = (int*)p;           p += (size_t)EA * 4;
    unsigned short* spad_a = (unsigned short*)p; p += (size_t)EA * 8;
    unsigned short* s_row  = (unsigned short*)p; p += (size_t)NS * 80 * 2;
    unsigned short* a_row  = (unsigned short*)p; p += (size_t)NA * 16 * 2;
    int*   bsum   = (int*)p;           p += 128 * 4;
    (void)ws_size;

    int* cnt_s = cnt2;
    int* cnt_a = cnt2 + NS;
    int* off_s = off2;
    int* off_a = off2 + NS;

    hipMemsetAsync(d_ws, 0, zbytes, stream);

    prep1<<<2048, 256, 0, stream>>>(pos_state, pos_action, h, x, u,
                                    s2s_dst, a2s_dst,
                                    s_row, a_row,
                                    cnt_s, rank_s, cnt_a, rank_a,
                                    NS, NA, ES, EA);
    scan_a<<<NB, 256, 0, stream>>>(cnt2, bsum, N2);
    scan_b<<<1, 128, 0, stream>>>(bsum, NB);
    scan_c<<<NB, 256, 0, stream>>>(cnt2, bsum, off2, N2, NS, ES);
    scatter_sort<<<1024, 256, 0, stream>>>(s2s_src, s2s_dst, rank_s, off_s,
                                           s2s_dis, pos_state,
                                           ssrc_s, sdst_s, spad_s, ES);
    scatter_sort<<<1024, 256, 0, stream>>>(a2s_src, a2s_dst, rank_a, off_a,
                                           a2s_dis, pos_state,
                                           ssrc_a, sdst_a, spad_a, EA);
    a2s_mfma<<<1024, 256, 0, stream>>>(a_row, ssrc_a, sdst_a, spad_a,
                                       u2h_w1, u2h_b1, u2h_w2, u2h_b2, u2h_w3, u2h_b3,
                                       sum_u, EA);
    s2s_mfma<<<1024, 256, 0, stream>>>(s_row, ssrc_s, sdst_s, spad_s,
                                       x2h_w1, x2h_b1, x2h_w2, x2h_b2, x2h_w3, x2h_b3,
                                       sum_x, ES);
    prep2<<<2048, 256, 0, stream>>>(pos_state, h, x, sum_u, sum_x, cnt_s, u_row, NS);
    upd_mfma<<<768, 256, 0, stream>>>(u_row,
                                      upd_w1, upd_b1, upd_w2, upd_b2, upd_w3, upd_b3,
                                      (float*)d_out, NS);
}

// Round 7
// 508.837 us; speedup vs baseline: 1.2892x; 1.0765x over previous
//
#include <hip/hip_runtime.h>
#include <hip/hip_bf16.h>

// R7: VALU diet on the MFMA kernels.
//  - bias folded into accumulator init (C-layout col-only dependence)
//  - v_cvt_pk_bf16_f32 packing via __float22bfloat162_rn
//  - weight fragment tables prebuilt once in global (build_wtab), blocks
//    preload LDS with b128 copies (kills conflicted b16 startup stores)
//  - emit loop: one address per sorted edge, imm-offset atomics, in-place merge
//  - merged scatter_sort, div-free prep2

typedef __attribute__((ext_vector_type(8))) short short8;
typedef __attribute__((ext_vector_type(4))) float f32x4;

#define MFMA(a, b, c) __builtin_amdgcn_mfma_f32_16x16x32_bf16(a, b, c, 0, 0, 0)

union FU { short8 v; unsigned int d[4]; unsigned short us[8]; };

__device__ __forceinline__ unsigned short f2bf(float f) {
    unsigned u = __float_as_uint(f);
    u += 0x7fffu + ((u >> 16) & 1u);   // RNE (data NaN-free)
    return (unsigned short)(u >> 16);
}
__device__ __forceinline__ unsigned int pack2(float a, float b) {
    return (unsigned int)f2bf(a) | ((unsigned int)f2bf(b) << 16);
}
__device__ __forceinline__ unsigned int pk2(float a, float b) {
    float2 t; t.x = a; t.y = b;
    union { __hip_bfloat162 h; unsigned int u; } c;
    c.h = __float22bfloat162_rn(t);     // v_cvt_pk_bf16_f32
    return c.u;
}
__device__ __forceinline__ float tanh_fast(float xv) {
    float t = __builtin_amdgcn_exp2f(xv * 2.8853900817779268f); // 2*log2(e)
    return 1.0f - 2.0f * __builtin_amdgcn_rcpf(t + 1.0f);
}

// Build weight fragment tables in GLOBAL memory (once).
// frag(c,nt): lane holds W[k = c*32 + (lane>>4)*8 + j][n = nt*16 + (lane&15)].
template <typename KM>
__device__ void build_gfrags(const float* __restrict__ w, unsigned short* dst,
                             int nchunks, int gtid, int gstr, KM km) {
    int total = nchunks * 4 * 64;
    for (int f = gtid; f < total; f += gstr) {
        int lv = f & 63, nt = (f >> 6) & 3, c = f >> 8;
        int n = nt * 16 + (lv & 15);
        int kb = c * 32 + ((lv >> 4) << 3);
        unsigned short* o = dst + f * 8;
        #pragma unroll
        for (int j = 0; j < 8; ++j) {
            int sk = km(kb + j);
            o[j] = (sk >= 0) ? f2bf(w[sk * 64 + n]) : (unsigned short)0;
        }
    }
}

#define PERM_KM [](int k) -> int { return (k >> 2) + 16 * (k & 3); }

__global__ __launch_bounds__(256) void build_wtab(
    const float* __restrict__ s_w1, const float* __restrict__ s_w2, const float* __restrict__ s_w3,
    const float* __restrict__ a_w1, const float* __restrict__ a_w2, const float* __restrict__ a_w3,
    const float* __restrict__ u_w1, const float* __restrict__ u_w2, const float* __restrict__ u_w3,
    unsigned short* __restrict__ ts, unsigned short* __restrict__ ta,
    unsigned short* __restrict__ tu)
{
    int gtid = blockIdx.x * 256 + threadIdx.x;
    int gstr = gridDim.x * 256;
    build_gfrags(s_w1, ts, 3, gtid, gstr, [](int k) -> int {
        if (k < 2)   return k;          // ps_src
        if (k < 74)  return k + 3;      // x, h
        if (k < 80)  return -2;
        if (k < 82)  return k - 78;     // ps_dst
        if (k == 82) return 4;          // dis
        return -2; });
    build_gfrags(s_w2, ts + 3 * 2048, 2, gtid, gstr, PERM_KM);
    build_gfrags(s_w3, ts + 5 * 2048, 2, gtid, gstr, PERM_KM);
    build_gfrags(a_w1, ta, 1, gtid, gstr, [](int k) -> int {
        if (k < 2)   return k;          // pa
        if (k < 10)  return k + 3;      // u
        if (k < 16)  return -2;
        if (k < 18)  return k - 14;     // ps_dst
        if (k == 18) return 4;          // dis
        return -2; });
    build_gfrags(a_w2, ta + 1 * 2048, 2, gtid, gstr, PERM_KM);
    build_gfrags(a_w3, ta + 3 * 2048, 2, gtid, gstr, PERM_KM);
    build_gfrags(u_w1, tu, 7, gtid, gstr, [](int k) -> int {
        return (k < 202) ? k : -2; });
    build_gfrags(u_w2, tu + 7 * 2048, 2, gtid, gstr, PERM_KM);
    build_gfrags(u_w3, tu + 9 * 2048, 2, gtid, gstr, PERM_KM);
}

// C-layout (lane q,m16 holds row=q*4+r, feat=nt*16+m16) -> Zb[row][kpos],
// kpos = 4*m16 + nt; row stride 72 elems.
#define ZTRANS(Zw, accv)                                                       \
    _Pragma("unroll")                                                          \
    for (int r = 0; r < 4; ++r) {                                              \
        uint2 pv;                                                              \
        pv.x = pk2(tanh_fast(accv[0][r]), tanh_fast(accv[1][r]));              \
        pv.y = pk2(tanh_fast(accv[2][r]), tanh_fast(accv[3][r]));              \
        *(uint2*)((Zw) + ((q << 2) + r) * 72 + (m16 << 2)) = pv;               \
    }

// ---------------------------------------------------------------------------
// prep1: bf16 row tables + per-dst counts & ranks
// ---------------------------------------------------------------------------
__global__ __launch_bounds__(256) void prep1(
    const float* __restrict__ ps, const float* __restrict__ pa,
    const float* __restrict__ h, const float* __restrict__ x,
    const float* __restrict__ u,
    const int* __restrict__ s2s_dst, const int* __restrict__ a2s_dst,
    unsigned short* __restrict__ s_row, unsigned short* __restrict__ a_row,
    int* __restrict__ cnt_s, int* __restrict__ rank_s,
    int* __restrict__ cnt_a, int* __restrict__ rank_a,
    int NS, int NA, int ES, int EA)
{
    int R0 = NS * 80, R1 = R0 + NA * 16, R2 = R1 + ES, R3 = R2 + EA;
    for (int i = blockIdx.x * 256 + threadIdx.x; i < R3; i += gridDim.x * 256) {
        if (i < R0) {
            int n = i / 80, k = i - n * 80;
            float v = (k < 2) ? ps[n * 2 + k] : (k < 10) ? x[n * 8 + k - 2]
                    : (k < 74) ? h[n * 64 + k - 10] : 0.f;
            s_row[i] = f2bf(v);
        } else if (i < R1) {
            int j = i - R0; int a = j / 16, k = j - a * 16;
            float v = (k < 2) ? pa[a * 2 + k] : (k < 10) ? u[a * 8 + k - 2] : 0.f;
            a_row[j] = f2bf(v);
        } else if (i < R2) {
            int e = i - R1;
            rank_s[e] = atomicAdd(&cnt_s[s2s_dst[e]], 1);
        } else {
            int e = i - R2;
            rank_a[e] = atomicAdd(&cnt_a[a2s_dst[e]], 1);
        }
    }
}

// ---------------------------------------------------------------------------
// 3-phase multi-block exclusive scan over concatenated [cnt_s | cnt_a].
// ---------------------------------------------------------------------------
#define SCAN_CHUNK 1024

__global__ __launch_bounds__(256) void scan_a(const int* __restrict__ cnt,
                                              int* __restrict__ bsum, int N2)
{
    __shared__ int red[256];
    int t = threadIdx.x;
    int base = blockIdx.x * SCAN_CHUNK + t * 4;
    int s = 0;
    #pragma unroll
    for (int j = 0; j < 4; ++j) { int i = base + j; if (i < N2) s += cnt[i]; }
    red[t] = s; __syncthreads();
    for (int d = 128; d > 0; d >>= 1) {
        if (t < d) red[t] += red[t + d];
        __syncthreads();
    }
    if (t == 0) bsum[blockIdx.x] = red[0];
}

__global__ __launch_bounds__(128) void scan_b(int* __restrict__ bsum, int NB)
{
    __shared__ int part[128];
    int t = threadIdx.x;
    int v = (t < NB) ? bsum[t] : 0;
    part[t] = v; __syncthreads();
    for (int d = 1; d < 128; d <<= 1) {
        int w = (t >= d) ? part[t - d] : 0;
        __syncthreads();
        part[t] += w;
        __syncthreads();
    }
    if (t < NB) bsum[t] = part[t] - v;
}

__global__ __launch_bounds__(256) void scan_c(const int* __restrict__ cnt,
                                              const int* __restrict__ bsum,
                                              int* __restrict__ off,
                                              int N2, int NS, int ES)
{
    __shared__ int part[256];
    int t = threadIdx.x;
    int base = blockIdx.x * SCAN_CHUNK + t * 4;
    int c[4]; int s = 0;
    #pragma unroll
    for (int j = 0; j < 4; ++j) { int i = base + j; c[j] = (i < N2) ? cnt[i] : 0; s += c[j]; }
    part[t] = s; __syncthreads();
    for (int d = 1; d < 256; d <<= 1) {
        int w = (t >= d) ? part[t - d] : 0;
        __syncthreads();
        part[t] += w;
        __syncthreads();
    }
    int run = bsum[blockIdx.x] + part[t] - s;
    #pragma unroll
    for (int j = 0; j < 4; ++j) {
        int i = base + j;
        if (i < N2) off[i] = run - ((i >= NS) ? ES : 0);
        run += c[j];
    }
}

// ---------------------------------------------------------------------------
// scatter_sort2: dst-sorted src/dst/pad for BOTH graphs in one launch.
// ---------------------------------------------------------------------------
__global__ __launch_bounds__(256) void scatter_sort2(
    const int* __restrict__ srcS, const int* __restrict__ dstS,
    const int* __restrict__ rankS, const int* __restrict__ offS,
    const float* __restrict__ disS,
    const int* __restrict__ srcA, const int* __restrict__ dstA,
    const int* __restrict__ rankA, const int* __restrict__ offA,
    const float* __restrict__ disA,
    const float* __restrict__ ps,
    int* __restrict__ ssrcS, int* __restrict__ sdstS, unsigned short* __restrict__ spadS,
    int* __restrict__ ssrcA, int* __restrict__ sdstA, unsigned short* __restrict__ spadA,
    int ES, int EA)
{
    int tot = ES + EA;
    for (int i = blockIdx.x * 256 + threadIdx.x; i < tot; i += gridDim.x * 256) {
        if (i < ES) {
            int d = dstS[i];
            int pos = offS[d] + rankS[i];
            ssrcS[pos] = srcS[i];
            sdstS[pos] = d;
            uint2 p;
            p.x = pack2(ps[d * 2], ps[d * 2 + 1]);
            p.y = (unsigned)f2bf(disS[i]) | (0x3F80u << 16);
            *(uint2*)(spadS + (size_t)pos * 4) = p;
        } else {
            int e = i - ES;
            int d = dstA[e];
            int pos = offA[d] + rankA[e];
            ssrcA[pos] = srcA[e];
            sdstA[pos] = d;
            uint2 p;
            p.x = pack2(ps[d * 2], ps[d * 2 + 1]);
            p.y = (unsigned)f2bf(disA[e]) | (0x3F80u << 16);
            *(uint2*)(spadA + (size_t)pos * 4) = p;
        }
    }
}

// ---------------------------------------------------------------------------
// s2s: sorted edges, K=96, segmented scatter. W-tables preloaded from global.
// ---------------------------------------------------------------------------
__global__ __launch_bounds__(256) void s2s_mfma(
    const unsigned short* __restrict__ s_row,
    const int* __restrict__ ssrc, const int* __restrict__ sdst,
    const unsigned short* __restrict__ spad,
    const unsigned short* __restrict__ wtab,
    const float* __restrict__ b1, const float* __restrict__ b2,
    const float* __restrict__ b3,
    float* __restrict__ sum_x, int E)
{
    __shared__ __align__(16) unsigned short WT[7 * 2048];   // 28 KB
    __shared__ __align__(16) unsigned short Z[4][16 * 72];

    int tid = threadIdx.x;
    for (int i = tid * 8; i < 7 * 2048; i += 256 * 8)
        *(short8*)(WT + i) = *(const short8*)(wtab + i);
    __syncthreads();

    const unsigned short* W1 = WT;
    const unsigned short* W2 = WT + 3 * 2048;
    const unsigned short* W3 = WT + 5 * 2048;

    int wid = tid >> 6, lane = tid & 63, m16 = lane & 15, q = lane >> 4;
    unsigned short* Zw = Z[wid];

    float bb1[4], bb2[4], bb3[4];
    #pragma unroll
    for (int nt = 0; nt < 4; ++nt) {
        bb1[nt] = b1[nt * 16 + m16];
        bb2[nt] = b2[nt * 16 + m16];
        bb3[nt] = b3[nt * 16 + m16];
    }

    int T = E >> 5;
    for (int t = blockIdx.x * 4 + wid; t < T; t += gridDim.x * 4) {
        int p0 = t * 32;
        int sp0 = p0 + ((m16 >> 2) << 3) + (m16 & 3);  // mt=0 A row
        int sp1 = sp0 + 4;                              // mt=1 A row
        int s0 = ssrc[sp0], s1 = ssrc[sp1];
        int pb = p0 + (q << 3);
        int4 dq0 = *(const int4*)(sdst + pb);
        int4 dq1 = *(const int4*)(sdst + pb + 4);
        int dseq[8] = {dq0.x, dq0.y, dq0.z, dq0.w, dq1.x, dq1.y, dq1.z, dq1.w};

        FU Lb[2][3]; uint2 ep[2];
        const unsigned short* rA = s_row + (size_t)s0 * 80;
        const unsigned short* rB = s_row + (size_t)s1 * 80;
        #pragma unroll
        for (int c = 0; c < 3; ++c) {
            Lb[0][c].v = *(const short8*)(rA + c * 32 + q * 8);
            Lb[1][c].v = *(const short8*)(rB + c * 32 + q * 8);
        }
        ep[0] = *(const uint2*)(spad + (size_t)sp0 * 4);
        ep[1] = *(const uint2*)(spad + (size_t)sp1 * 4);
        #pragma unroll
        for (int mt = 0; mt < 2; ++mt) {            // chunk 2: q2=pad, q3=0
            FU f = Lb[mt][2];
            f.d[0] = q < 2 ? f.d[0] : (q == 2 ? ep[mt].x : 0u);
            f.d[1] = q < 2 ? f.d[1] : (q == 2 ? ep[mt].y : 0u);
            f.d[2] = q < 2 ? f.d[2] : 0u;
            f.d[3] = q < 2 ? f.d[3] : 0u;
            Lb[mt][2] = f;
        }

        f32x4 acc1[2][4];
        #pragma unroll
        for (int mt = 0; mt < 2; ++mt)
            #pragma unroll
            for (int nt = 0; nt < 4; ++nt)
                acc1[mt][nt] = (f32x4){bb1[nt], bb1[nt], bb1[nt], bb1[nt]};
        #pragma unroll
        for (int c = 0; c < 3; ++c)
            #pragma unroll
            for (int nt = 0; nt < 4; ++nt) {
                short8 wf = *(const short8*)(W1 + ((c * 4 + nt) * 64 + lane) * 8);
                acc1[0][nt] = MFMA(Lb[0][c].v, wf, acc1[0][nt]);
                acc1[1][nt] = MFMA(Lb[1][c].v, wf, acc1[1][nt]);
            }

        f32x4 a3[2][4];
        #pragma unroll
        for (int mt = 0; mt < 2; ++mt) {
            ZTRANS(Zw, acc1[mt])
            FU A2[2];
            A2[0].v = *(const short8*)(Zw + m16 * 72 + 0 * 32 + q * 8);
            A2[1].v = *(const short8*)(Zw + m16 * 72 + 1 * 32 + q * 8);

            f32x4 a2[4];
            #pragma unroll
            for (int nt = 0; nt < 4; ++nt) {
                a2[nt] = (f32x4){bb2[nt], bb2[nt], bb2[nt], bb2[nt]};
                short8 w0 = *(const short8*)(W2 + ((0 * 4 + nt) * 64 + lane) * 8);
                short8 w1f = *(const short8*)(W2 + ((1 * 4 + nt) * 64 + lane) * 8);
                a2[nt] = MFMA(A2[0].v, w0, a2[nt]);
                a2[nt] = MFMA(A2[1].v, w1f, a2[nt]);
            }

            ZTRANS(Zw, a2)
            FU A3[2];
            A3[0].v = *(const short8*)(Zw + m16 * 72 + 0 * 32 + q * 8);
            A3[1].v = *(const short8*)(Zw + m16 * 72 + 1 * 32 + q * 8);

            #pragma unroll
            for (int nt = 0; nt < 4; ++nt) {
                a3[mt][nt] = (f32x4){bb3[nt], bb3[nt], bb3[nt], bb3[nt]};
                short8 w0 = *(const short8*)(W3 + ((0 * 4 + nt) * 64 + lane) * 8);
                short8 w1f = *(const short8*)(W3 + ((1 * 4 + nt) * 64 + lane) * 8);
                a3[mt][nt] = MFMA(A3[0].v, w0, a3[mt][nt]);
                a3[mt][nt] = MFMA(A3[1].v, w1f, a3[mt][nt]);
            }
        }

        // segmented emit: in-place run-merge, one base addr per edge, imm-offset atomics
        #pragma unroll
        for (int j = 0; j < 8; ++j) {
            int mt = j >> 2, r = j & 3;
            bool merge = (j < 7) && (dseq[j] == dseq[j + 1]);
            if (merge) {
                int mt2 = (j + 1) >> 2, r2 = (j + 1) & 3;
                #pragma unroll
                for (int nt = 0; nt < 4; ++nt) a3[mt2][nt][r2] += a3[mt][nt][r];
            } else {
                float* pbase = sum_x + (size_t)dseq[j] * 64 + m16;
                #pragma unroll
                for (int nt = 0; nt < 4; ++nt)
                    unsafeAtomicAdd(pbase + nt * 16, a3[mt][nt][r]);
            }
        }
    }
}

// ---------------------------------------------------------------------------
// a2s: sorted edges, K=32, segmented scatter.
// ---------------------------------------------------------------------------
__global__ __launch_bounds__(256) void a2s_mfma(
    const unsigned short* __restrict__ a_row,
    const int* __restrict__ ssrc, const int* __restrict__ sdst,
    const unsigned short* __restrict__ spad,
    const unsigned short* __restrict__ wtab,
    const float* __restrict__ b1, const float* __restrict__ b2,
    const float* __restrict__ b3,
    float* __restrict__ sum_u, int E)
{
    __shared__ __align__(16) unsigned short WT[5 * 2048];   // 20 KB
    __shared__ __align__(16) unsigned short Z[4][16 * 72];

    int tid = threadIdx.x;
    for (int i = tid * 8; i < 5 * 2048; i += 256 * 8)
        *(short8*)(WT + i) = *(const short8*)(wtab + i);
    __syncthreads();

    const unsigned short* W1 = WT;
    const unsigned short* W2 = WT + 1 * 2048;
    const unsigned short* W3 = WT + 3 * 2048;

    int wid = tid >> 6, lane = tid & 63, m16 = lane & 15, q = lane >> 4;
    unsigned short* Zw = Z[wid];

    float bb1[4], bb2[4], bb3[4];
    #pragma unroll
    for (int nt = 0; nt < 4; ++nt) {
        bb1[nt] = b1[nt * 16 + m16];
        bb2[nt] = b2[nt * 16 + m16];
        bb3[nt] = b3[nt * 16 + m16];
    }

    int T = E >> 5;
    for (int t = blockIdx.x * 4 + wid; t < T; t += gridDim.x * 4) {
        int p0 = t * 32;
        int sp0 = p0 + ((m16 >> 2) << 3) + (m16 & 3);
        int sp1 = sp0 + 4;
        int s0 = ssrc[sp0], s1 = ssrc[sp1];
        int pb = p0 + (q << 3);
        int4 dq0 = *(const int4*)(sdst + pb);
        int4 dq1 = *(const int4*)(sdst + pb + 4);
        int dseq[8] = {dq0.x, dq0.y, dq0.z, dq0.w, dq1.x, dq1.y, dq1.z, dq1.w};

        FU Lb[2]; uint2 ep[2];
        Lb[0].v = *(const short8*)(a_row + (size_t)s0 * 16 + q * 8);
        Lb[1].v = *(const short8*)(a_row + (size_t)s1 * 16 + q * 8);
        ep[0] = *(const uint2*)(spad + (size_t)sp0 * 4);
        ep[1] = *(const uint2*)(spad + (size_t)sp1 * 4);
        #pragma unroll
        for (int mt = 0; mt < 2; ++mt) {   // q0,1 = a_row; q2 = pad; q3 = 0
            FU f = Lb[mt];
            f.d[0] = q < 2 ? f.d[0] : (q == 2 ? ep[mt].x : 0u);
            f.d[1] = q < 2 ? f.d[1] : (q == 2 ? ep[mt].y : 0u);
            f.d[2] = q < 2 ? f.d[2] : 0u;
            f.d[3] = q < 2 ? f.d[3] : 0u;
            Lb[mt] = f;
        }

        f32x4 acc1[2][4];
        #pragma unroll
        for (int mt = 0; mt < 2; ++mt)
            #pragma unroll
            for (int nt = 0; nt < 4; ++nt)
                acc1[mt][nt] = (f32x4){bb1[nt], bb1[nt], bb1[nt], bb1[nt]};
        #pragma unroll
        for (int nt = 0; nt < 4; ++nt) {
            short8 wf = *(const short8*)(W1 + (nt * 64 + lane) * 8);
            acc1[0][nt] = MFMA(Lb[0].v, wf, acc1[0][nt]);
            acc1[1][nt] = MFMA(Lb[1].v, wf, acc1[1][nt]);
        }

        f32x4 a3[2][4];
        #pragma unroll
        for (int mt = 0; mt < 2; ++mt) {
            ZTRANS(Zw, acc1[mt])
            FU A2[2];
            A2[0].v = *(const short8*)(Zw + m16 * 72 + 0 * 32 + q * 8);
            A2[1].v = *(const short8*)(Zw + m16 * 72 + 1 * 32 + q * 8);

            f32x4 a2[4];
            #pragma unroll
            for (int nt = 0; nt < 4; ++nt) {
                a2[nt] = (f32x4){bb2[nt], bb2[nt], bb2[nt], bb2[nt]};
                short8 w0 = *(const short8*)(W2 + ((0 * 4 + nt) * 64 + lane) * 8);
                short8 w1f = *(const short8*)(W2 + ((1 * 4 + nt) * 64 + lane) * 8);
                a2[nt] = MFMA(A2[0].v, w0, a2[nt]);
                a2[nt] = MFMA(A2[1].v, w1f, a2[nt]);
            }

            ZTRANS(Zw, a2)
            FU A3[2];
            A3[0].v = *(const short8*)(Zw + m16 * 72 + 0 * 32 + q * 8);
            A3[1].v = *(const short8*)(Zw + m16 * 72 + 1 * 32 + q * 8);

            #pragma unroll
            for (int nt = 0; nt < 4; ++nt) {
                a3[mt][nt] = (f32x4){bb3[nt], bb3[nt], bb3[nt], bb3[nt]};
                short8 w0 = *(const short8*)(W3 + ((0 * 4 + nt) * 64 + lane) * 8);
                short8 w1f = *(const short8*)(W3 + ((1 * 4 + nt) * 64 + lane) * 8);
                a3[mt][nt] = MFMA(A3[0].v, w0, a3[mt][nt]);
                a3[mt][nt] = MFMA(A3[1].v, w1f, a3[mt][nt]);
            }
        }

        #pragma unroll
        for (int j = 0; j < 8; ++j) {
            int mt = j >> 2, r = j & 3;
            bool merge = (j < 7) && (dseq[j] == dseq[j + 1]);
            if (merge) {
                int mt2 = (j + 1) >> 2, r2 = (j + 1) & 3;
                #pragma unroll
                for (int nt = 0; nt < 4; ++nt) a3[mt2][nt][r2] += a3[mt][nt][r];
            } else {
                float* pbase = sum_u + (size_t)dseq[j] * 64 + m16;
                #pragma unroll
                for (int nt = 0; nt < 4; ++nt)
                    unsafeAtomicAdd(pbase + nt * 16, a3[mt][nt][r]);
            }
        }
    }
}

// ---------------------------------------------------------------------------
// prep2: u_row[n][224], block-per-node (no div); bias slots -> 0.
// ---------------------------------------------------------------------------
__global__ __launch_bounds__(256) void prep2(
    const float* __restrict__ ps, const float* __restrict__ h,
    const float* __restrict__ x,
    const float* __restrict__ su, const float* __restrict__ sx,
    const int* __restrict__ cnt_s, unsigned short* __restrict__ u_row, int NS)
{
    int n = blockIdx.x;
    int k = threadIdx.x;
    if (k >= 224) return;
    float v;
    if (k < 2)        v = ps[n * 2 + k];
    else if (k < 66)  v = h[n * 64 + k - 2];
    else if (k < 130) v = su[n * 64 + k - 66];
    else if (k < 194) v = sx[n * 64 + k - 130] * (1.0f / fmaxf((float)cnt_s[n], 1.0f));
    else if (k < 202) v = x[n * 8 + k - 194];
    else              v = 0.f;
    u_row[(size_t)n * 224 + k] = f2bf(v);
}

// ---------------------------------------------------------------------------
// upd: K=224 from u_row, 16 nodes/wave, row-contiguous store.
// ---------------------------------------------------------------------------
__global__ __launch_bounds__(256) void upd_mfma(
    const unsigned short* __restrict__ u_row,
    const unsigned short* __restrict__ wtab,
    const float* __restrict__ b1, const float* __restrict__ b2,
    const float* __restrict__ b3,
    float* __restrict__ out, int NS)
{
    __shared__ __align__(16) unsigned short WT[11 * 2048];  // 44 KB
    __shared__ __align__(16) unsigned short Z[4][16 * 72];

    int tid = threadIdx.x;
    for (int i = tid * 8; i < 11 * 2048; i += 256 * 8)
        *(short8*)(WT + i) = *(const short8*)(wtab + i);
    __syncthreads();

    const unsigned short* W1 = WT;
    const unsigned short* W2 = WT + 7 * 2048;
    const unsigned short* W3 = WT + 9 * 2048;

    int wid = tid >> 6, lane = tid & 63, m16 = lane & 15, q = lane >> 4;
    unsigned short* Zw = Z[wid];

    float bb1[4], bb2[4], bb3[4];
    #pragma unroll
    for (int nt = 0; nt < 4; ++nt) {
        bb1[nt] = b1[nt * 16 + m16];
        bb2[nt] = b2[nt * 16 + m16];
        bb3[nt] = b3[nt * 16 + m16];
    }

    int T = NS >> 4;
    for (int t = blockIdx.x * 4 + wid; t < T; t += gridDim.x * 4) {
        int n0 = t * 16;
        const unsigned short* row = u_row + (size_t)(n0 + m16) * 224;

        f32x4 acc1[4];
        #pragma unroll
        for (int nt = 0; nt < 4; ++nt)
            acc1[nt] = (f32x4){bb1[nt], bb1[nt], bb1[nt], bb1[nt]};
        #pragma unroll
        for (int c = 0; c < 7; ++c) {
            short8 afrag = *(const short8*)(row + c * 32 + q * 8);
            #pragma unroll
            for (int nt = 0; nt < 4; ++nt) {
                short8 wf = *(const short8*)(W1 + ((c * 4 + nt) * 64 + lane) * 8);
                acc1[nt] = MFMA(afrag, wf, acc1[nt]);
            }
        }

        ZTRANS(Zw, acc1)
        FU A2[2];
        A2[0].v = *(const short8*)(Zw + m16 * 72 + 0 * 32 + q * 8);
        A2[1].v = *(const short8*)(Zw + m16 * 72 + 1 * 32 + q * 8);

        f32x4 a2[4];
        #pragma unroll
        for (int nt = 0; nt < 4; ++nt) {
            a2[nt] = (f32x4){bb2[nt], bb2[nt], bb2[nt], bb2[nt]};
            short8 w0 = *(const short8*)(W2 + ((0 * 4 + nt) * 64 + lane) * 8);
            short8 w1f = *(const short8*)(W2 + ((1 * 4 + nt) * 64 + lane) * 8);
            a2[nt] = MFMA(A2[0].v, w0, a2[nt]);
            a2[nt] = MFMA(A2[1].v, w1f, a2[nt]);
        }

        ZTRANS(Zw, a2)
        FU A3[2];
        A3[0].v = *(const short8*)(Zw + m16 * 72 + 0 * 32 + q * 8);
        A3[1].v = *(const short8*)(Zw + m16 * 72 + 1 * 32 + q * 8);

        f32x4 a3[4];
        #pragma unroll
        for (int nt = 0; nt < 4; ++nt) {
            a3[nt] = (f32x4){bb3[nt], bb3[nt], bb3[nt], bb3[nt]};
            short8 w0 = *(const short8*)(W3 + ((0 * 4 + nt) * 64 + lane) * 8);
            short8 w1f = *(const short8*)(W3 + ((1 * 4 + nt) * 64 + lane) * 8);
            a3[nt] = MFMA(A3[0].v, w0, a3[nt]);
            a3[nt] = MFMA(A3[1].v, w1f, a3[nt]);
        }

        #pragma unroll
        for (int nt = 0; nt < 4; ++nt)
            #pragma unroll
            for (int r = 0; r < 4; ++r)
                out[(size_t)(n0 + (q << 2) + r) * 64 + nt * 16 + m16] = a3[nt][r];
    }
}

extern "C" void kernel_launch(void* const* d_in, const int* in_sizes, int n_in,
                              void* d_out, int out_size, void* d_ws, size_t ws_size,
                              hipStream_t stream) {
    const float* pos_state  = (const float*)d_in[0];
    const float* pos_action = (const float*)d_in[1];
    const float* h          = (const float*)d_in[2];
    const float* x          = (const float*)d_in[3];
    const float* u          = (const float*)d_in[4];
    const int*   a2s_src    = (const int*)d_in[5];
    const int*   a2s_dst    = (const int*)d_in[6];
    const float* a2s_dis    = (const float*)d_in[7];
    const int*   s2s_src    = (const int*)d_in[8];
    const int*   s2s_dst    = (const int*)d_in[9];
    const float* s2s_dis    = (const float*)d_in[10];
    const float* u2h_w1 = (const float*)d_in[11]; const float* u2h_b1 = (const float*)d_in[12];
    const float* u2h_w2 = (const float*)d_in[13]; const float* u2h_b2 = (const float*)d_in[14];
    const float* u2h_w3 = (const float*)d_in[15]; const float* u2h_b3 = (const float*)d_in[16];
    const float* x2h_w1 = (const float*)d_in[17]; const float* x2h_b1 = (const float*)d_in[18];
    const float* x2h_w2 = (const float*)d_in[19]; const float* x2h_b2 = (const float*)d_in[20];
    const float* x2h_w3 = (const float*)d_in[21]; const float* x2h_b3 = (const float*)d_in[22];
    const float* upd_w1 = (const float*)d_in[23]; const float* upd_b1 = (const float*)d_in[24];
    const float* upd_w2 = (const float*)d_in[25]; const float* upd_b2 = (const float*)d_in[26];
    const float* upd_w3 = (const float*)d_in[27]; const float* upd_b3 = (const float*)d_in[28];

    int NS = in_sizes[0] / 2;
    int NA = in_sizes[1] / 2;
    int EA = in_sizes[5];
    int ES = in_sizes[8];
    int N2 = 2 * NS;
    int NB = (N2 + SCAN_CHUNK - 1) / SCAN_CHUNK;

    char* p = (char*)d_ws;
    int*   cnt2  = (int*)p;            p += (size_t)N2 * 4;       // cnt_s | cnt_a
    float* sum_u = (float*)p;          p += (size_t)NS * 64 * 4;
    float* sum_x = (float*)p;          p += (size_t)NS * 64 * 4;
    size_t zbytes = (size_t)(p - (char*)d_ws);
    unsigned short* u_row = (unsigned short*)p;  // alias window, dead until prep2
    int*   off2   = (int*)p;           p += (size_t)N2 * 4;
    int*   rank_s = (int*)p;           p += (size_t)ES * 4;
    int*   rank_a = (int*)p;           p += (size_t)EA * 4;
    int*   ssrc_s = (int*)p;           p += (size_t)ES * 4;
    int*   sdst_s = (int*)p;           p += (size_t)ES * 4;
    unsigned short* spad_s = (unsigned short*)p; p += (size_t)ES * 8;
    // u_row (NS*224*2 = 22.4 MB) ends here; below survives past prep2
    int*   ssrc_a = (int*)p;           p += (size_t)EA * 4;
    int*   sdst_a = (int*)p;           p += (size_t)EA * 4;
    unsigned short* spad_a = (unsigned short*)p; p += (size_t)EA * 8;
    unsigned short* s_row  = (unsigned short*)p; p += (size_t)NS * 80 * 2;
    unsigned short* a_row  = (unsigned short*)p; p += (size_t)NA * 16 * 2;
    int*   bsum   = (int*)p;           p += 128 * 4;
    unsigned short* wtab_s = (unsigned short*)p; p += 7 * 2048 * 2;
    unsigned short* wtab_a = (unsigned short*)p; p += 5 * 2048 * 2;
    unsigned short* wtab_u = (unsigned short*)p; p += 11 * 2048 * 2;
    (void)ws_size;

    int* cnt_s = cnt2;
    int* cnt_a = cnt2 + NS;
    int* off_s = off2;
    int* off_a = off2 + NS;

    hipMemsetAsync(d_ws, 0, zbytes, stream);

    build_wtab<<<24, 256, 0, stream>>>(x2h_w1, x2h_w2, x2h_w3,
                                       u2h_w1, u2h_w2, u2h_w3,
                                       upd_w1, upd_w2, upd_w3,
                                       wtab_s, wtab_a, wtab_u);
    prep1<<<2048, 256, 0, stream>>>(pos_state, pos_action, h, x, u,
                                    s2s_dst, a2s_dst,
                                    s_row, a_row,
                                    cnt_s, rank_s, cnt_a, rank_a,
                                    NS, NA, ES, EA);
    scan_a<<<NB, 256, 0, stream>>>(cnt2, bsum, N2);
    scan_b<<<1, 128, 0, stream>>>(bsum, NB);
    scan_c<<<NB, 256, 0, stream>>>(cnt2, bsum, off2, N2, NS, ES);
    scatter_sort2<<<1024, 256, 0, stream>>>(s2s_src, s2s_dst, rank_s, off_s, s2s_dis,
                                            a2s_src, a2s_dst, rank_a, off_a, a2s_dis,
                                            pos_state,
                                            ssrc_s, sdst_s, spad_s,
                                            ssrc_a, sdst_a, spad_a, ES, EA);
    a2s_mfma<<<1024, 256, 0, stream>>>(a_row, ssrc_a, sdst_a, spad_a, wtab_a,
                                       u2h_b1, u2h_b2, u2h_b3, sum_u, EA);
    s2s_mfma<<<1024, 256, 0, stream>>>(s_row, ssrc_s, sdst_s, spad_s, wtab_s,
                                       x2h_b1, x2h_b2, x2h_b3, sum_x, ES);
    prep2<<<NS, 256, 0, stream>>>(pos_state, h, x, sum_u, sum_x, cnt_s, u_row, NS);
    upd_mfma<<<784, 256, 0, stream>>>(u_row, wtab_u,
                                      upd_b1, upd_b2, upd_b3,
                                      (float*)d_out, NS);
}

// Round 8
// 445.941 us; speedup vs baseline: 1.4710x; 1.1410x over previous
//
#include <hip/hip_runtime.h>
#include <hip/hip_bf16.h>

// R8: structural fusion round.
//  - prep2 eliminated: upd_w1 K-order permuted to [h|su|sxm|ps,x] so upd gathers
//    fp32 h/sum_u/sum_x directly (float4 + v_cvt_pk) -- no u_row round-trip.
//  - scatter stores 12B/edge (ssrc/sdst/sdis); edge kernels rebuild the bf16
//    pad from ps[dst] on q==2 lanes.
//  - a2s+s2s merged into one dispatch (block-range split) -- HW backfills.
//  - build_wtab folded into prep1 (+24 blocks).

typedef __attribute__((ext_vector_type(8))) short short8;
typedef __attribute__((ext_vector_type(4))) float f32x4;

#define MFMA(a, b, c) __builtin_amdgcn_mfma_f32_16x16x32_bf16(a, b, c, 0, 0, 0)

union FU { short8 v; unsigned int d[4]; unsigned short us[8]; };

__device__ __forceinline__ unsigned short f2bf(float f) {
    unsigned u = __float_as_uint(f);
    u += 0x7fffu + ((u >> 16) & 1u);   // RNE (data NaN-free)
    return (unsigned short)(u >> 16);
}
__device__ __forceinline__ unsigned int pk2(float a, float b) {
    float2 t; t.x = a; t.y = b;
    union { __hip_bfloat162 h; unsigned int u; } c;
    c.h = __float22bfloat162_rn(t);     // v_cvt_pk_bf16_f32
    return c.u;
}
__device__ __forceinline__ float tanh_fast(float xv) {
    float t = __builtin_amdgcn_exp2f(xv * 2.8853900817779268f); // 2*log2(e)
    return 1.0f - 2.0f * __builtin_amdgcn_rcpf(t + 1.0f);
}

// Build weight fragment tables in GLOBAL memory (once).
// frag(c,nt): lane holds W[k = c*32 + (lane>>4)*8 + j][n = nt*16 + (lane&15)].
template <typename KM>
__device__ void build_gfrags(const float* __restrict__ w, unsigned short* dst,
                             int nchunks, int gtid, int gstr, KM km) {
    int total = nchunks * 4 * 64;
    for (int f = gtid; f < total; f += gstr) {
        int lv = f & 63, nt = (f >> 6) & 3, c = f >> 8;
        int n = nt * 16 + (lv & 15);
        int kb = c * 32 + ((lv >> 4) << 3);
        unsigned short* o = dst + f * 8;
        #pragma unroll
        for (int j = 0; j < 8; ++j) {
            int sk = km(kb + j);
            o[j] = (sk >= 0) ? f2bf(w[sk * 64 + n]) : (unsigned short)0;
        }
    }
}

#define PERM_KM [](int k) -> int { return (k >> 2) + 16 * (k & 3); }

// C-layout (lane q,m16 holds row=q*4+r, feat=nt*16+m16) -> Zb[row][kpos],
// kpos = 4*m16 + nt; row stride 72 elems.
#define ZTRANS(Zw, accv)                                                       \
    _Pragma("unroll")                                                          \
    for (int r = 0; r < 4; ++r) {                                              \
        uint2 pv;                                                              \
        pv.x = pk2(tanh_fast(accv[0][r]), tanh_fast(accv[1][r]));              \
        pv.y = pk2(tanh_fast(accv[2][r]), tanh_fast(accv[3][r]));              \
        *(uint2*)((Zw) + ((q << 2) + r) * 72 + (m16 << 2)) = pv;               \
    }

// ---------------------------------------------------------------------------
// prep1: bf16 row tables + per-dst counts & ranks + (extra blocks) wtab build
// ---------------------------------------------------------------------------
__global__ __launch_bounds__(256) void prep1(
    const float* __restrict__ ps, const float* __restrict__ pa,
    const float* __restrict__ h, const float* __restrict__ x,
    const float* __restrict__ u,
    const int* __restrict__ s2s_dst, const int* __restrict__ a2s_dst,
    unsigned short* __restrict__ s_row, unsigned short* __restrict__ a_row,
    int* __restrict__ cnt_s, int* __restrict__ rank_s,
    int* __restrict__ cnt_a, int* __restrict__ rank_a,
    const float* __restrict__ s_w1, const float* __restrict__ s_w2, const float* __restrict__ s_w3,
    const float* __restrict__ a_w1, const float* __restrict__ a_w2, const float* __restrict__ a_w3,
    const float* __restrict__ u_w1, const float* __restrict__ u_w2, const float* __restrict__ u_w3,
    unsigned short* __restrict__ ts, unsigned short* __restrict__ ta,
    unsigned short* __restrict__ tu,
    int NS, int NA, int ES, int EA, int MAINB)
{
    int bid = blockIdx.x;
    if (bid >= MAINB) {
        int gtid = (bid - MAINB) * 256 + threadIdx.x;
        int gstr = (gridDim.x - MAINB) * 256;
        build_gfrags(s_w1, ts, 3, gtid, gstr, [](int k) -> int {
            if (k < 2)   return k;          // ps_src
            if (k < 74)  return k + 3;      // x, h
            if (k < 80)  return -2;
            if (k < 82)  return k - 78;     // ps_dst
            if (k == 82) return 4;          // dis
            return -2; });
        build_gfrags(s_w2, ts + 3 * 2048, 2, gtid, gstr, PERM_KM);
        build_gfrags(s_w3, ts + 5 * 2048, 2, gtid, gstr, PERM_KM);
        build_gfrags(a_w1, ta, 1, gtid, gstr, [](int k) -> int {
            if (k < 2)   return k;          // pa
            if (k < 10)  return k + 3;      // u
            if (k < 16)  return -2;
            if (k < 18)  return k - 14;     // ps_dst
            if (k == 18) return 4;          // dis
            return -2; });
        build_gfrags(a_w2, ta + 1 * 2048, 2, gtid, gstr, PERM_KM);
        build_gfrags(a_w3, ta + 3 * 2048, 2, gtid, gstr, PERM_KM);
        // upd W1 with K-order [h(64) | su(64) | sxm(64) | ps(2), x(8)]
        build_gfrags(u_w1, tu, 7, gtid, gstr, [](int k) -> int {
            if (k < 192) return k + 2;      // h, su, sxm (orig 2..193)
            if (k < 194) return k - 192;    // ps (orig 0,1)
            if (k < 202) return k;          // x (orig 194..201)
            return -2; });
        build_gfrags(u_w2, tu + 7 * 2048, 2, gtid, gstr, PERM_KM);
        build_gfrags(u_w3, tu + 9 * 2048, 2, gtid, gstr, PERM_KM);
        return;
    }

    int R0 = NS * 80, R1 = R0 + NA * 16, R2 = R1 + ES, R3 = R2 + EA;
    for (int i = bid * 256 + threadIdx.x; i < R3; i += MAINB * 256) {
        if (i < R0) {
            int n = i / 80, k = i - n * 80;
            float v = (k < 2) ? ps[n * 2 + k] : (k < 10) ? x[n * 8 + k - 2]
                    : (k < 74) ? h[n * 64 + k - 10] : 0.f;
            s_row[i] = f2bf(v);
        } else if (i < R1) {
            int j = i - R0; int a = j / 16, k = j - a * 16;
            float v = (k < 2) ? pa[a * 2 + k] : (k < 10) ? u[a * 8 + k - 2] : 0.f;
            a_row[j] = f2bf(v);
        } else if (i < R2) {
            int e = i - R1;
            rank_s[e] = atomicAdd(&cnt_s[s2s_dst[e]], 1);
        } else {
            int e = i - R2;
            rank_a[e] = atomicAdd(&cnt_a[a2s_dst[e]], 1);
        }
    }
}

// ---------------------------------------------------------------------------
// 3-phase multi-block exclusive scan over concatenated [cnt_s | cnt_a].
// ---------------------------------------------------------------------------
#define SCAN_CHUNK 1024

__global__ __launch_bounds__(256) void scan_a(const int* __restrict__ cnt,
                                              int* __restrict__ bsum, int N2)
{
    __shared__ int red[256];
    int t = threadIdx.x;
    int base = blockIdx.x * SCAN_CHUNK + t * 4;
    int s = 0;
    #pragma unroll
    for (int j = 0; j < 4; ++j) { int i = base + j; if (i < N2) s += cnt[i]; }
    red[t] = s; __syncthreads();
    for (int d = 128; d > 0; d >>= 1) {
        if (t < d) red[t] += red[t + d];
        __syncthreads();
    }
    if (t == 0) bsum[blockIdx.x] = red[0];
}

__global__ __launch_bounds__(128) void scan_b(int* __restrict__ bsum, int NB)
{
    __shared__ int part[128];
    int t = threadIdx.x;
    int v = (t < NB) ? bsum[t] : 0;
    part[t] = v; __syncthreads();
    for (int d = 1; d < 128; d <<= 1) {
        int w = (t >= d) ? part[t - d] : 0;
        __syncthreads();
        part[t] += w;
        __syncthreads();
    }
    if (t < NB) bsum[t] = part[t] - v;
}

__global__ __launch_bounds__(256) void scan_c(const int* __restrict__ cnt,
                                              const int* __restrict__ bsum,
                                              int* __restrict__ off,
                                              int N2, int NS, int ES)
{
    __shared__ int part[256];
    int t = threadIdx.x;
    int base = blockIdx.x * SCAN_CHUNK + t * 4;
    int c[4]; int s = 0;
    #pragma unroll
    for (int j = 0; j < 4; ++j) { int i = base + j; c[j] = (i < N2) ? cnt[i] : 0; s += c[j]; }
    part[t] = s; __syncthreads();
    for (int d = 1; d < 256; d <<= 1) {
        int w = (t >= d) ? part[t - d] : 0;
        __syncthreads();
        part[t] += w;
        __syncthreads();
    }
    int run = bsum[blockIdx.x] + part[t] - s;
    #pragma unroll
    for (int j = 0; j < 4; ++j) {
        int i = base + j;
        if (i < N2) off[i] = run - ((i >= NS) ? ES : 0);
        run += c[j];
    }
}

// ---------------------------------------------------------------------------
// scatter_sort2: dst-sorted (src, dst, dis) for BOTH graphs; 12B/edge.
// ---------------------------------------------------------------------------
__global__ __launch_bounds__(256) void scatter_sort2(
    const int* __restrict__ srcS, const int* __restrict__ dstS,
    const int* __restrict__ rankS, const int* __restrict__ offS,
    const float* __restrict__ disS,
    const int* __restrict__ srcA, const int* __restrict__ dstA,
    const int* __restrict__ rankA, const int* __restrict__ offA,
    const float* __restrict__ disA,
    int* __restrict__ ssrcS, int* __restrict__ sdstS, float* __restrict__ sdisS,
    int* __restrict__ ssrcA, int* __restrict__ sdstA, float* __restrict__ sdisA,
    int ES, int EA)
{
    int tot = ES + EA;
    for (int i = blockIdx.x * 256 + threadIdx.x; i < tot; i += gridDim.x * 256) {
        if (i < ES) {
            int d = dstS[i];
            int pos = offS[d] + rankS[i];
            ssrcS[pos] = srcS[i];
            sdstS[pos] = d;
            sdisS[pos] = disS[i];
        } else {
            int e = i - ES;
            int d = dstA[e];
            int pos = offA[d] + rankA[e];
            ssrcA[pos] = srcA[e];
            sdstA[pos] = d;
            sdisA[pos] = disA[e];
        }
    }
}

// ---------------------------------------------------------------------------
// edge_path: 3-layer edge MLP over sorted edges, segmented atomic emit.
// C1 = layer-1 chunk count; RS = row-table stride (= C1*32 - 16).
// ---------------------------------------------------------------------------
template <int C1, int RS>
__device__ __forceinline__ void edge_path(
    const unsigned short* __restrict__ row_tab,
    const int* __restrict__ ssrc, const int* __restrict__ sdst,
    const float* __restrict__ sdis, const float* __restrict__ ps,
    const unsigned short* WT,
    const float* __restrict__ b1, const float* __restrict__ b2,
    const float* __restrict__ b3,
    float* __restrict__ sums, int E, int bid0, int nb, int tid,
    unsigned short* Zbase)
{
    const unsigned short* W1 = WT;
    const unsigned short* W2 = WT + C1 * 2048;
    const unsigned short* W3 = WT + (C1 + 2) * 2048;

    int wid = tid >> 6, lane = tid & 63, m16 = lane & 15, q = lane >> 4;
    unsigned short* Zw = Zbase + wid * (16 * 72);

    float bb1[4], bb2[4], bb3[4];
    #pragma unroll
    for (int nt = 0; nt < 4; ++nt) {
        bb1[nt] = b1[nt * 16 + m16];
        bb2[nt] = b2[nt * 16 + m16];
        bb3[nt] = b3[nt * 16 + m16];
    }

    int T = E >> 5;
    for (int t = bid0 * 4 + wid; t < T; t += nb * 4) {
        int p0 = t * 32;
        int sp0 = p0 + ((m16 >> 2) << 3) + (m16 & 3);  // mt=0 A row
        int sp1 = sp0 + 4;                              // mt=1 A row
        int s0 = ssrc[sp0], s1 = ssrc[sp1];
        int pb = p0 + (q << 3);
        int4 dq0 = *(const int4*)(sdst + pb);
        int4 dq1 = *(const int4*)(sdst + pb + 4);
        int dseq[8] = {dq0.x, dq0.y, dq0.z, dq0.w, dq1.x, dq1.y, dq1.z, dq1.w};

        uint2 ep[2];
        ep[0].x = 0; ep[0].y = 0; ep[1].x = 0; ep[1].y = 0;
        if (q == 2) {   // pad lanes: {ps[d], dis, 1.0}
            int dA = sdst[sp0], dB = sdst[sp1];
            float2 pA = *(const float2*)(ps + 2 * dA);
            float2 pB = *(const float2*)(ps + 2 * dB);
            float zA = sdis[sp0], zB = sdis[sp1];
            ep[0].x = pk2(pA.x, pA.y); ep[0].y = (unsigned)f2bf(zA) | (0x3F80u << 16);
            ep[1].x = pk2(pB.x, pB.y); ep[1].y = (unsigned)f2bf(zB) | (0x3F80u << 16);
        }

        FU Lb[2][C1];
        const unsigned short* rA = row_tab + (size_t)s0 * RS;
        const unsigned short* rB = row_tab + (size_t)s1 * RS;
        #pragma unroll
        for (int c = 0; c < C1; ++c) {
            int off = c * 32 + q * 8;
            bool valid = (c < C1 - 1) || (q < 2);
            if (valid) {
                Lb[0][c].v = *(const short8*)(rA + off);
                Lb[1][c].v = *(const short8*)(rB + off);
            } else {
                Lb[0][c].d[0] = ep[0].x; Lb[0][c].d[1] = ep[0].y; Lb[0][c].d[2] = 0; Lb[0][c].d[3] = 0;
                Lb[1][c].d[0] = ep[1].x; Lb[1][c].d[1] = ep[1].y; Lb[1][c].d[2] = 0; Lb[1][c].d[3] = 0;
            }
        }

        f32x4 acc1[2][4];
        #pragma unroll
        for (int mt = 0; mt < 2; ++mt)
            #pragma unroll
            for (int nt = 0; nt < 4; ++nt)
                acc1[mt][nt] = (f32x4){bb1[nt], bb1[nt], bb1[nt], bb1[nt]};
        #pragma unroll
        for (int c = 0; c < C1; ++c)
            #pragma unroll
            for (int nt = 0; nt < 4; ++nt) {
                short8 wf = *(const short8*)(W1 + ((c * 4 + nt) * 64 + lane) * 8);
                acc1[0][nt] = MFMA(Lb[0][c].v, wf, acc1[0][nt]);
                acc1[1][nt] = MFMA(Lb[1][c].v, wf, acc1[1][nt]);
            }

        f32x4 a3[2][4];
        #pragma unroll
        for (int mt = 0; mt < 2; ++mt) {
            ZTRANS(Zw, acc1[mt])
            FU A2[2];
            A2[0].v = *(const short8*)(Zw + m16 * 72 + 0 * 32 + q * 8);
            A2[1].v = *(const short8*)(Zw + m16 * 72 + 1 * 32 + q * 8);

            f32x4 a2[4];
            #pragma unroll
            for (int nt = 0; nt < 4; ++nt) {
                a2[nt] = (f32x4){bb2[nt], bb2[nt], bb2[nt], bb2[nt]};
                short8 w0 = *(const short8*)(W2 + ((0 * 4 + nt) * 64 + lane) * 8);
                short8 w1f = *(const short8*)(W2 + ((1 * 4 + nt) * 64 + lane) * 8);
                a2[nt] = MFMA(A2[0].v, w0, a2[nt]);
                a2[nt] = MFMA(A2[1].v, w1f, a2[nt]);
            }

            ZTRANS(Zw, a2)
            FU A3[2];
            A3[0].v = *(const short8*)(Zw + m16 * 72 + 0 * 32 + q * 8);
            A3[1].v = *(const short8*)(Zw + m16 * 72 + 1 * 32 + q * 8);

            #pragma unroll
            for (int nt = 0; nt < 4; ++nt) {
                a3[mt][nt] = (f32x4){bb3[nt], bb3[nt], bb3[nt], bb3[nt]};
                short8 w0 = *(const short8*)(W3 + ((0 * 4 + nt) * 64 + lane) * 8);
                short8 w1f = *(const short8*)(W3 + ((1 * 4 + nt) * 64 + lane) * 8);
                a3[mt][nt] = MFMA(A3[0].v, w0, a3[mt][nt]);
                a3[mt][nt] = MFMA(A3[1].v, w1f, a3[mt][nt]);
            }
        }

        // segmented emit: in-place run-merge, one base addr per edge
        #pragma unroll
        for (int j = 0; j < 8; ++j) {
            int mt = j >> 2, r = j & 3;
            bool merge = (j < 7) && (dseq[j] == dseq[j + 1]);
            if (merge) {
                int mt2 = (j + 1) >> 2, r2 = (j + 1) & 3;
                #pragma unroll
                for (int nt = 0; nt < 4; ++nt) a3[mt2][nt][r2] += a3[mt][nt][r];
            } else {
                float* pbase = sums + (size_t)dseq[j] * 64 + m16;
                #pragma unroll
                for (int nt = 0; nt < 4; ++nt)
                    unsafeAtomicAdd(pbase + nt * 16, a3[mt][nt][r]);
            }
        }
    }
}

// ---------------------------------------------------------------------------
// edges_mfma: s2s (blocks < SPLIT) and a2s (blocks >= SPLIT) in one dispatch.
// ---------------------------------------------------------------------------
__global__ __launch_bounds__(256) void edges_mfma(
    const unsigned short* __restrict__ s_row, const unsigned short* __restrict__ a_row,
    const int* __restrict__ ssS, const int* __restrict__ sdS, const float* __restrict__ szS,
    const int* __restrict__ ssA, const int* __restrict__ sdA, const float* __restrict__ szA,
    const unsigned short* __restrict__ wtS, const unsigned short* __restrict__ wtA,
    const float* __restrict__ sb1, const float* __restrict__ sb2, const float* __restrict__ sb3,
    const float* __restrict__ ab1, const float* __restrict__ ab2, const float* __restrict__ ab3,
    const float* __restrict__ ps,
    float* __restrict__ sum_x, float* __restrict__ sum_u,
    int ES, int EA, int SPLIT)
{
    __shared__ __align__(16) unsigned short WT[7 * 2048];
    __shared__ __align__(16) unsigned short Z[4][16 * 72];

    int tid = threadIdx.x, bid = blockIdx.x;
    bool is_s = bid < SPLIT;
    const unsigned short* wt = is_s ? wtS : wtA;
    int wtn = is_s ? 7 * 2048 : 5 * 2048;
    for (int i = tid * 8; i < wtn; i += 256 * 8)
        *(short8*)(WT + i) = *(const short8*)(wt + i);
    __syncthreads();

    if (is_s)
        edge_path<3, 80>(s_row, ssS, sdS, szS, ps, WT, sb1, sb2, sb3,
                         sum_x, ES, bid, SPLIT, tid, &Z[0][0]);
    else
        edge_path<1, 16>(a_row, ssA, sdA, szA, ps, WT, ab1, ab2, ab3,
                         sum_u, EA, bid - SPLIT, gridDim.x - SPLIT, tid, &Z[0][0]);
}

// ---------------------------------------------------------------------------
// upd: fused gather (fp32 h/su/sxm/ps/x -> bf16 A-frags in-reg), K=224.
// Feature order matches prep1's permuted u_w1: [h | su | sxm | ps, x].
// ---------------------------------------------------------------------------
__global__ __launch_bounds__(256) void upd_mfma(
    const float* __restrict__ ps, const float* __restrict__ h,
    const float* __restrict__ x,
    const float* __restrict__ su, const float* __restrict__ sx,
    const int* __restrict__ cnt_s,
    const unsigned short* __restrict__ wtab,
    const float* __restrict__ b1, const float* __restrict__ b2,
    const float* __restrict__ b3,
    float* __restrict__ out, int NS)
{
    __shared__ __align__(16) unsigned short WT[11 * 2048];  // 44 KB
    __shared__ __align__(16) unsigned short Z[4][16 * 72];

    int tid = threadIdx.x;
    for (int i = tid * 8; i < 11 * 2048; i += 256 * 8)
        *(short8*)(WT + i) = *(const short8*)(wtab + i);
    __syncthreads();

    const unsigned short* W1 = WT;
    const unsigned short* W2 = WT + 7 * 2048;
    const unsigned short* W3 = WT + 9 * 2048;

    int wid = tid >> 6, lane = tid & 63, m16 = lane & 15, q = lane >> 4;
    unsigned short* Zw = &Z[wid][0];

    float bb1[4], bb2[4], bb3[4];
    #pragma unroll
    for (int nt = 0; nt < 4; ++nt) {
        bb1[nt] = b1[nt * 16 + m16];
        bb2[nt] = b2[nt * 16 + m16];
        bb3[nt] = b3[nt * 16 + m16];
    }

    int T = NS >> 4;
    for (int t = blockIdx.x * 4 + wid; t < T; t += gridDim.x * 4) {
        int n0 = t * 16;
        int n = n0 + m16;
        float rd = __builtin_amdgcn_rcpf(fmaxf((float)cnt_s[n], 1.0f));

        // A-frags: c=0,1 from h; 2,3 from su; 4,5 from sx*rd; 6 piecewise
        FU A[7];
        const float* hp = h + (size_t)n * 64;
        const float* sup = su + (size_t)n * 64;
        const float* sxp = sx + (size_t)n * 64;
        #pragma unroll
        for (int c = 0; c < 6; ++c) {
            const float* src = (c < 2) ? hp : (c < 4) ? sup : sxp;
            int base = (c & 1) * 32 + q * 8;
            float4 f0 = *(const float4*)(src + base);
            float4 f1 = *(const float4*)(src + base + 4);
            if (c >= 4) {
                f0.x *= rd; f0.y *= rd; f0.z *= rd; f0.w *= rd;
                f1.x *= rd; f1.y *= rd; f1.z *= rd; f1.w *= rd;
            }
            A[c].d[0] = pk2(f0.x, f0.y); A[c].d[1] = pk2(f0.z, f0.w);
            A[c].d[2] = pk2(f1.x, f1.y); A[c].d[3] = pk2(f1.z, f1.w);
        }
        A[6].d[0] = 0; A[6].d[1] = 0; A[6].d[2] = 0; A[6].d[3] = 0;
        if (q == 0) {
            float2 pp = *(const float2*)(ps + 2 * n);
            float4 x0 = *(const float4*)(x + 8 * n);
            float2 x1 = *(const float2*)(x + 8 * n + 4);
            A[6].d[0] = pk2(pp.x, pp.y);
            A[6].d[1] = pk2(x0.x, x0.y);
            A[6].d[2] = pk2(x0.z, x0.w);
            A[6].d[3] = pk2(x1.x, x1.y);
        } else if (q == 1) {
            float2 x2 = *(const float2*)(x + 8 * n + 6);
            A[6].d[0] = pk2(x2.x, x2.y);
        }

        f32x4 acc1[4];
        #pragma unroll
        for (int nt = 0; nt < 4; ++nt)
            acc1[nt] = (f32x4){bb1[nt], bb1[nt], bb1[nt], bb1[nt]};
        #pragma unroll
        for (int c = 0; c < 7; ++c)
            #pragma unroll
            for (int nt = 0; nt < 4; ++nt) {
                short8 wf = *(const short8*)(W1 + ((c * 4 + nt) * 64 + lane) * 8);
                acc1[nt] = MFMA(A[c].v, wf, acc1[nt]);
            }

        ZTRANS(Zw, acc1)
        FU A2[2];
        A2[0].v = *(const short8*)(Zw + m16 * 72 + 0 * 32 + q * 8);
        A2[1].v = *(const short8*)(Zw + m16 * 72 + 1 * 32 + q * 8);

        f32x4 a2[4];
        #pragma unroll
        for (int nt = 0; nt < 4; ++nt) {
            a2[nt] = (f32x4){bb2[nt], bb2[nt], bb2[nt], bb2[nt]};
            short8 w0 = *(const short8*)(W2 + ((0 * 4 + nt) * 64 + lane) * 8);
            short8 w1f = *(const short8*)(W2 + ((1 * 4 + nt) * 64 + lane) * 8);
            a2[nt] = MFMA(A2[0].v, w0, a2[nt]);
            a2[nt] = MFMA(A2[1].v, w1f, a2[nt]);
        }

        ZTRANS(Zw, a2)
        FU A3[2];
        A3[0].v = *(const short8*)(Zw + m16 * 72 + 0 * 32 + q * 8);
        A3[1].v = *(const short8*)(Zw + m16 * 72 + 1 * 32 + q * 8);

        f32x4 a3[4];
        #pragma unroll
        for (int nt = 0; nt < 4; ++nt) {
            a3[nt] = (f32x4){bb3[nt], bb3[nt], bb3[nt], bb3[nt]};
            short8 w0 = *(const short8*)(W3 + ((0 * 4 + nt) * 64 + lane) * 8);
            short8 w1f = *(const short8*)(W3 + ((1 * 4 + nt) * 64 + lane) * 8);
            a3[nt] = MFMA(A3[0].v, w0, a3[nt]);
            a3[nt] = MFMA(A3[1].v, w1f, a3[nt]);
        }

        #pragma unroll
        for (int nt = 0; nt < 4; ++nt)
            #pragma unroll
            for (int r = 0; r < 4; ++r)
                out[(size_t)(n0 + (q << 2) + r) * 64 + nt * 16 + m16] = a3[nt][r];
    }
}

extern "C" void kernel_launch(void* const* d_in, const int* in_sizes, int n_in,
                              void* d_out, int out_size, void* d_ws, size_t ws_size,
                              hipStream_t stream) {
    const float* pos_state  = (const float*)d_in[0];
    const float* pos_action = (const float*)d_in[1];
    const float* h          = (const float*)d_in[2];
    const float* x          = (const float*)d_in[3];
    const float* u          = (const float*)d_in[4];
    const int*   a2s_src    = (const int*)d_in[5];
    const int*   a2s_dst    = (const int*)d_in[6];
    const float* a2s_dis    = (const float*)d_in[7];
    const int*   s2s_src    = (const int*)d_in[8];
    const int*   s2s_dst    = (const int*)d_in[9];
    const float* s2s_dis    = (const float*)d_in[10];
    const float* u2h_w1 = (const float*)d_in[11]; const float* u2h_b1 = (const float*)d_in[12];
    const float* u2h_w2 = (const float*)d_in[13]; const float* u2h_b2 = (const float*)d_in[14];
    const float* u2h_w3 = (const float*)d_in[15]; const float* u2h_b3 = (const float*)d_in[16];
    const float* x2h_w1 = (const float*)d_in[17]; const float* x2h_b1 = (const float*)d_in[18];
    const float* x2h_w2 = (const float*)d_in[19]; const float* x2h_b2 = (const float*)d_in[20];
    const float* x2h_w3 = (const float*)d_in[21]; const float* x2h_b3 = (const float*)d_in[22];
    const float* upd_w1 = (const float*)d_in[23]; const float* upd_b1 = (const float*)d_in[24];
    const float* upd_w2 = (const float*)d_in[25]; const float* upd_b2 = (const float*)d_in[26];
    const float* upd_w3 = (const float*)d_in[27]; const float* upd_b3 = (const float*)d_in[28];

    int NS = in_sizes[0] / 2;
    int NA = in_sizes[1] / 2;
    int EA = in_sizes[5];
    int ES = in_sizes[8];
    int N2 = 2 * NS;
    int NB = (N2 + SCAN_CHUNK - 1) / SCAN_CHUNK;

    char* p = (char*)d_ws;
    int*   cnt2  = (int*)p;            p += (size_t)N2 * 4;       // cnt_s | cnt_a
    float* sum_u = (float*)p;          p += (size_t)NS * 64 * 4;
    float* sum_x = (float*)p;          p += (size_t)NS * 64 * 4;
    size_t zbytes = (size_t)(p - (char*)d_ws);
    int*   off2   = (int*)p;           p += (size_t)N2 * 4;
    int*   rank_s = (int*)p;           p += (size_t)ES * 4;
    int*   rank_a = (int*)p;           p += (size_t)EA * 4;
    int*   ssrc_s = (int*)p;           p += (size_t)ES * 4;
    int*   sdst_s = (int*)p;           p += (size_t)ES * 4;
    float* sdis_s = (float*)p;         p += (size_t)ES * 4;
    int*   ssrc_a = (int*)p;           p += (size_t)EA * 4;
    int*   sdst_a = (int*)p;           p += (size_t)EA * 4;
    float* sdis_a = (float*)p;         p += (size_t)EA * 4;
    unsigned short* s_row  = (unsigned short*)p; p += (size_t)NS * 80 * 2;
    unsigned short* a_row  = (unsigned short*)p; p += (size_t)NA * 16 * 2;
    int*   bsum   = (int*)p;           p += 128 * 4;
    unsigned short* wtab_s = (unsigned short*)p; p += 7 * 2048 * 2;
    unsigned short* wtab_a = (unsigned short*)p; p += 5 * 2048 * 2;
    unsigned short* wtab_u = (unsigned short*)p; p += 11 * 2048 * 2;
    (void)ws_size;

    int* cnt_s = cnt2;
    int* cnt_a = cnt2 + NS;
    int* off_s = off2;
    int* off_a = off2 + NS;

    hipMemsetAsync(d_ws, 0, zbytes, stream);

    const int MAINB = 2048;
    prep1<<<MAINB + 24, 256, 0, stream>>>(pos_state, pos_action, h, x, u,
                                          s2s_dst, a2s_dst, s_row, a_row,
                                          cnt_s, rank_s, cnt_a, rank_a,
                                          x2h_w1, x2h_w2, x2h_w3,
                                          u2h_w1, u2h_w2, u2h_w3,
                                          upd_w1, upd_w2, upd_w3,
                                          wtab_s, wtab_a, wtab_u,
                                          NS, NA, ES, EA, MAINB);
    scan_a<<<NB, 256, 0, stream>>>(cnt2, bsum, N2);
    scan_b<<<1, 128, 0, stream>>>(bsum, NB);
    scan_c<<<NB, 256, 0, stream>>>(cnt2, bsum, off2, N2, NS, ES);
    scatter_sort2<<<1024, 256, 0, stream>>>(s2s_src, s2s_dst, rank_s, off_s, s2s_dis,
                                            a2s_src, a2s_dst, rank_a, off_a, a2s_dis,
                                            ssrc_s, sdst_s, sdis_s,
                                            ssrc_a, sdst_a, sdis_a, ES, EA);
    edges_mfma<<<1536, 256, 0, stream>>>(s_row, a_row,
                                         ssrc_s, sdst_s, sdis_s,
                                         ssrc_a, sdst_a, sdis_a,
                                         wtab_s, wtab_a,
                                         x2h_b1, x2h_b2, x2h_b3,
                                         u2h_b1, u2h_b2, u2h_b3,
                                         pos_state, sum_x, sum_u,
                                         ES, EA, 1024);
    upd_mfma<<<784, 256, 0, stream>>>(pos_state, h, x, sum_u, sum_x, cnt_s,
                                      wtab_u, upd_b1, upd_b2, upd_b3,
                                      (float*)d_out, NS);
}

// Round 9
// 423.326 us; speedup vs baseline: 1.5496x; 1.0534x over previous
//
#include <hip/hip_runtime.h>
#include <hip/hip_bf16.h>

// R9: overhead consolidation.
//  - prep1 row tables: padded shift/mask indexing (no idiv), 4-elem v_cvt_pk
//    uint2 stores (9.8M scalar iters -> 1.8M vector iters)
//  - memset only cnt2; sum_u/sum_x zeroed inside scatter_sort2
//  - scatter stores 2 packets/edge: {src,dis} 8B struct + dst array
//  - edges_mfma SPLIT rebalanced 1120/416

typedef __attribute__((ext_vector_type(8))) short short8;
typedef __attribute__((ext_vector_type(4))) float f32x4;

#define MFMA(a, b, c) __builtin_amdgcn_mfma_f32_16x16x32_bf16(a, b, c, 0, 0, 0)

union FU { short8 v; unsigned int d[4]; unsigned short us[8]; };

__device__ __forceinline__ unsigned short f2bf(float f) {
    unsigned u = __float_as_uint(f);
    u += 0x7fffu + ((u >> 16) & 1u);   // RNE (data NaN-free)
    return (unsigned short)(u >> 16);
}
__device__ __forceinline__ unsigned int pk2(float a, float b) {
    float2 t; t.x = a; t.y = b;
    union { __hip_bfloat162 h; unsigned int u; } c;
    c.h = __float22bfloat162_rn(t);     // v_cvt_pk_bf16_f32
    return c.u;
}
__device__ __forceinline__ float tanh_fast(float xv) {
    float t = __builtin_amdgcn_exp2f(xv * 2.8853900817779268f); // 2*log2(e)
    return 1.0f - 2.0f * __builtin_amdgcn_rcpf(t + 1.0f);
}

// Build weight fragment tables in GLOBAL memory (once).
// frag(c,nt): lane holds W[k = c*32 + (lane>>4)*8 + j][n = nt*16 + (lane&15)].
template <typename KM>
__device__ void build_gfrags(const float* __restrict__ w, unsigned short* dst,
                             int nchunks, int gtid, int gstr, KM km) {
    int total = nchunks * 4 * 64;
    for (int f = gtid; f < total; f += gstr) {
        int lv = f & 63, nt = (f >> 6) & 3, c = f >> 8;
        int n = nt * 16 + (lv & 15);
        int kb = c * 32 + ((lv >> 4) << 3);
        unsigned short* o = dst + f * 8;
        #pragma unroll
        for (int j = 0; j < 8; ++j) {
            int sk = km(kb + j);
            o[j] = (sk >= 0) ? f2bf(w[sk * 64 + n]) : (unsigned short)0;
        }
    }
}

#define PERM_KM [](int k) -> int { return (k >> 2) + 16 * (k & 3); }

// C-layout (lane q,m16 holds row=q*4+r, feat=nt*16+m16) -> Zb[row][kpos],
// kpos = 4*m16 + nt; row stride 72 elems.
#define ZTRANS(Zw, accv)                                                       \
    _Pragma("unroll")                                                          \
    for (int r = 0; r < 4; ++r) {                                              \
        uint2 pv;                                                              \
        pv.x = pk2(tanh_fast(accv[0][r]), tanh_fast(accv[1][r]));              \
        pv.y = pk2(tanh_fast(accv[2][r]), tanh_fast(accv[3][r]));              \
        *(uint2*)((Zw) + ((q << 2) + r) * 72 + (m16 << 2)) = pv;               \
    }

// ---------------------------------------------------------------------------
// prep1: bf16 row tables (vectorized) + per-dst counts & ranks + wtab build
// ---------------------------------------------------------------------------
__global__ __launch_bounds__(256) void prep1(
    const float* __restrict__ ps, const float* __restrict__ pa,
    const float* __restrict__ h, const float* __restrict__ x,
    const float* __restrict__ u,
    const int* __restrict__ s2s_dst, const int* __restrict__ a2s_dst,
    unsigned short* __restrict__ s_row, unsigned short* __restrict__ a_row,
    int* __restrict__ cnt_s, int* __restrict__ rank_s,
    int* __restrict__ cnt_a, int* __restrict__ rank_a,
    const float* __restrict__ s_w1, const float* __restrict__ s_w2, const float* __restrict__ s_w3,
    const float* __restrict__ a_w1, const float* __restrict__ a_w2, const float* __restrict__ a_w3,
    const float* __restrict__ u_w1, const float* __restrict__ u_w2, const float* __restrict__ u_w3,
    unsigned short* __restrict__ ts, unsigned short* __restrict__ ta,
    unsigned short* __restrict__ tu,
    int NS, int NA, int ES, int EA, int MAINB)
{
    int bid = blockIdx.x;
    if (bid >= MAINB) {
        int gtid = (bid - MAINB) * 256 + threadIdx.x;
        int gstr = (gridDim.x - MAINB) * 256;
        build_gfrags(s_w1, ts, 3, gtid, gstr, [](int k) -> int {
            if (k < 2)   return k;          // ps_src
            if (k < 74)  return k + 3;      // x, h
            if (k < 80)  return -2;
            if (k < 82)  return k - 78;     // ps_dst
            if (k == 82) return 4;          // dis
            return -2; });
        build_gfrags(s_w2, ts + 3 * 2048, 2, gtid, gstr, PERM_KM);
        build_gfrags(s_w3, ts + 5 * 2048, 2, gtid, gstr, PERM_KM);
        build_gfrags(a_w1, ta, 1, gtid, gstr, [](int k) -> int {
            if (k < 2)   return k;          // pa
            if (k < 10)  return k + 3;      // u
            if (k < 16)  return -2;
            if (k < 18)  return k - 14;     // ps_dst
            if (k == 18) return 4;          // dis
            return -2; });
        build_gfrags(a_w2, ta + 1 * 2048, 2, gtid, gstr, PERM_KM);
        build_gfrags(a_w3, ta + 3 * 2048, 2, gtid, gstr, PERM_KM);
        // upd W1 with K-order [h(64) | su(64) | sxm(64) | ps(2), x(8)]
        build_gfrags(u_w1, tu, 7, gtid, gstr, [](int k) -> int {
            if (k < 192) return k + 2;      // h, su, sxm (orig 2..193)
            if (k < 194) return k - 192;    // ps (orig 0,1)
            if (k < 202) return k;          // x (orig 194..201)
            return -2; });
        build_gfrags(u_w2, tu + 7 * 2048, 2, gtid, gstr, PERM_KM);
        build_gfrags(u_w3, tu + 9 * 2048, 2, gtid, gstr, PERM_KM);
        return;
    }

    // padded index spaces: s_row NS*32 (20 active of 32), a_row NA*4, ranks
    int R0 = NS * 32, R1 = R0 + NA * 4, R2 = R1 + ES, R3 = R2 + EA;
    for (int i = bid * 256 + threadIdx.x; i < R3; i += MAINB * 256) {
        if (i < R0) {
            int n = i >> 5, kq = i & 31;
            if (kq < 20) {
                int k0 = kq << 2;
                float f[4];
                #pragma unroll
                for (int j = 0; j < 4; ++j) {
                    int k = k0 + j;
                    f[j] = (k < 2) ? ps[n * 2 + k] : (k < 10) ? x[n * 8 + k - 2]
                         : (k < 74) ? h[n * 64 + k - 10] : 0.f;
                }
                uint2 o; o.x = pk2(f[0], f[1]); o.y = pk2(f[2], f[3]);
                *(uint2*)&s_row[(size_t)n * 80 + k0] = o;
            }
        } else if (i < R1) {
            int j2 = i - R0; int a = j2 >> 2, kq = j2 & 3;
            int k0 = kq << 2;
            float f[4];
            #pragma unroll
            for (int j = 0; j < 4; ++j) {
                int k = k0 + j;
                f[j] = (k < 2) ? pa[a * 2 + k] : (k < 10) ? u[a * 8 + k - 2] : 0.f;
            }
            uint2 o; o.x = pk2(f[0], f[1]); o.y = pk2(f[2], f[3]);
            *(uint2*)&a_row[(size_t)a * 16 + k0] = o;
        } else if (i < R2) {
            int e = i - R1;
            rank_s[e] = atomicAdd(&cnt_s[s2s_dst[e]], 1);
        } else {
            int e = i - R2;
            rank_a[e] = atomicAdd(&cnt_a[a2s_dst[e]], 1);
        }
    }
}

// ---------------------------------------------------------------------------
// 3-phase multi-block exclusive scan over concatenated [cnt_s | cnt_a].
// ---------------------------------------------------------------------------
#define SCAN_CHUNK 1024

__global__ __launch_bounds__(256) void scan_a(const int* __restrict__ cnt,
                                              int* __restrict__ bsum, int N2)
{
    __shared__ int red[256];
    int t = threadIdx.x;
    int base = blockIdx.x * SCAN_CHUNK + t * 4;
    int s = 0;
    #pragma unroll
    for (int j = 0; j < 4; ++j) { int i = base + j; if (i < N2) s += cnt[i]; }
    red[t] = s; __syncthreads();
    for (int d = 128; d > 0; d >>= 1) {
        if (t < d) red[t] += red[t + d];
        __syncthreads();
    }
    if (t == 0) bsum[blockIdx.x] = red[0];
}

__global__ __launch_bounds__(128) void scan_b(int* __restrict__ bsum, int NB)
{
    __shared__ int part[128];
    int t = threadIdx.x;
    int v = (t < NB) ? bsum[t] : 0;
    part[t] = v; __syncthreads();
    for (int d = 1; d < 128; d <<= 1) {
        int w = (t >= d) ? part[t - d] : 0;
        __syncthreads();
        part[t] += w;
        __syncthreads();
    }
    if (t < NB) bsum[t] = part[t] - v;
}

__global__ __launch_bounds__(256) void scan_c(const int* __restrict__ cnt,
                                              const int* __restrict__ bsum,
                                              int* __restrict__ off,
                                              int N2, int NS, int ES)
{
    __shared__ int part[256];
    int t = threadIdx.x;
    int base = blockIdx.x * SCAN_CHUNK + t * 4;
    int c[4]; int s = 0;
    #pragma unroll
    for (int j = 0; j < 4; ++j) { int i = base + j; c[j] = (i < N2) ? cnt[i] : 0; s += c[j]; }
    part[t] = s; __syncthreads();
    for (int d = 1; d < 256; d <<= 1) {
        int w = (t >= d) ? part[t - d] : 0;
        __syncthreads();
        part[t] += w;
        __syncthreads();
    }
    int run = bsum[blockIdx.x] + part[t] - s;
    #pragma unroll
    for (int j = 0; j < 4; ++j) {
        int i = base + j;
        if (i < N2) off[i] = run - ((i >= NS) ? ES : 0);
        run += c[j];
    }
}

// ---------------------------------------------------------------------------
// scatter_sort2: dst-sorted ({src,dis} 8B + dst) for BOTH graphs,
// plus zeroing of sum_u/sum_x (contiguous NS*128 floats).
// ---------------------------------------------------------------------------
__global__ __launch_bounds__(256) void scatter_sort2(
    const int* __restrict__ srcS, const int* __restrict__ dstS,
    const int* __restrict__ rankS, const int* __restrict__ offS,
    const float* __restrict__ disS,
    const int* __restrict__ srcA, const int* __restrict__ dstA,
    const int* __restrict__ rankA, const int* __restrict__ offA,
    const float* __restrict__ disA,
    uint2* __restrict__ sdS, int* __restrict__ sdstS,
    uint2* __restrict__ sdA, int* __restrict__ sdstA,
    float* __restrict__ sums, int ES, int EA, int NZ4)
{
    int gtid = blockIdx.x * 256 + threadIdx.x;
    int gstr = gridDim.x * 256;
    // zero sum_u | sum_x (NZ4 float4's)
    for (int i = gtid; i < NZ4; i += gstr)
        ((f32x4*)sums)[i] = (f32x4){0.f, 0.f, 0.f, 0.f};
    int tot = ES + EA;
    for (int i = gtid; i < tot; i += gstr) {
        if (i < ES) {
            int d = dstS[i];
            int pos = offS[d] + rankS[i];
            uint2 v; v.x = (unsigned)srcS[i]; v.y = __float_as_uint(disS[i]);
            sdS[pos] = v;
            sdstS[pos] = d;
        } else {
            int e = i - ES;
            int d = dstA[e];
            int pos = offA[d] + rankA[e];
            uint2 v; v.x = (unsigned)srcA[e]; v.y = __float_as_uint(disA[e]);
            sdA[pos] = v;
            sdstA[pos] = d;
        }
    }
}

// ---------------------------------------------------------------------------
// edge_path: 3-layer edge MLP over sorted edges, segmented atomic emit.
// C1 = layer-1 chunk count; RS = row-table stride.
// ---------------------------------------------------------------------------
template <int C1, int RS>
__device__ __forceinline__ void edge_path(
    const unsigned short* __restrict__ row_tab,
    const uint2* __restrict__ srcdis, const int* __restrict__ sdst,
    const float* __restrict__ ps,
    const unsigned short* WT,
    const float* __restrict__ b1, const float* __restrict__ b2,
    const float* __restrict__ b3,
    float* __restrict__ sums, int E, int bid0, int nb, int tid,
    unsigned short* Zbase)
{
    const unsigned short* W1 = WT;
    const unsigned short* W2 = WT + C1 * 2048;
    const unsigned short* W3 = WT + (C1 + 2) * 2048;

    int wid = tid >> 6, lane = tid & 63, m16 = lane & 15, q = lane >> 4;
    unsigned short* Zw = Zbase + wid * (16 * 72);

    float bb1[4], bb2[4], bb3[4];
    #pragma unroll
    for (int nt = 0; nt < 4; ++nt) {
        bb1[nt] = b1[nt * 16 + m16];
        bb2[nt] = b2[nt * 16 + m16];
        bb3[nt] = b3[nt * 16 + m16];
    }

    int T = E >> 5;
    for (int t = bid0 * 4 + wid; t < T; t += nb * 4) {
        int p0 = t * 32;
        int sp0 = p0 + ((m16 >> 2) << 3) + (m16 & 3);  // mt=0 A row
        int sp1 = sp0 + 4;                              // mt=1 A row
        uint2 sd0 = srcdis[sp0], sd1 = srcdis[sp1];
        int s0 = (int)sd0.x, s1 = (int)sd1.x;
        int pb = p0 + (q << 3);
        int4 dq0 = *(const int4*)(sdst + pb);
        int4 dq1 = *(const int4*)(sdst + pb + 4);
        int dseq[8] = {dq0.x, dq0.y, dq0.z, dq0.w, dq1.x, dq1.y, dq1.z, dq1.w};

        uint2 ep[2];
        ep[0].x = 0; ep[0].y = 0; ep[1].x = 0; ep[1].y = 0;
        if (q == 2) {   // pad lanes: {ps[d], dis, 1.0}
            int dA = sdst[sp0], dB = sdst[sp1];
            float2 pA = *(const float2*)(ps + 2 * dA);
            float2 pB = *(const float2*)(ps + 2 * dB);
            ep[0].x = pk2(pA.x, pA.y);
            ep[0].y = (unsigned)f2bf(__uint_as_float(sd0.y)) | (0x3F80u << 16);
            ep[1].x = pk2(pB.x, pB.y);
            ep[1].y = (unsigned)f2bf(__uint_as_float(sd1.y)) | (0x3F80u << 16);
        }

        FU Lb[2][C1];
        const unsigned short* rA = row_tab + (size_t)s0 * RS;
        const unsigned short* rB = row_tab + (size_t)s1 * RS;
        #pragma unroll
        for (int c = 0; c < C1; ++c) {
            int off = c * 32 + q * 8;
            bool valid = (c < C1 - 1) || (q < 2);
            if (valid) {
                Lb[0][c].v = *(const short8*)(rA + off);
                Lb[1][c].v = *(const short8*)(rB + off);
            } else {
                Lb[0][c].d[0] = ep[0].x; Lb[0][c].d[1] = ep[0].y; Lb[0][c].d[2] = 0; Lb[0][c].d[3] = 0;
                Lb[1][c].d[0] = ep[1].x; Lb[1][c].d[1] = ep[1].y; Lb[1][c].d[2] = 0; Lb[1][c].d[3] = 0;
            }
        }

        f32x4 acc1[2][4];
        #pragma unroll
        for (int mt = 0; mt < 2; ++mt)
            #pragma unroll
            for (int nt = 0; nt < 4; ++nt)
                acc1[mt][nt] = (f32x4){bb1[nt], bb1[nt], bb1[nt], bb1[nt]};
        #pragma unroll
        for (int c = 0; c < C1; ++c)
            #pragma unroll
            for (int nt = 0; nt < 4; ++nt) {
                short8 wf = *(const short8*)(W1 + ((c * 4 + nt) * 64 + lane) * 8);
                acc1[0][nt] = MFMA(Lb[0][c].v, wf, acc1[0][nt]);
                acc1[1][nt] = MFMA(Lb[1][c].v, wf, acc1[1][nt]);
            }

        f32x4 a3[2][4];
        #pragma unroll
        for (int mt = 0; mt < 2; ++mt) {
            ZTRANS(Zw, acc1[mt])
            FU A2[2];
            A2[0].v = *(const short8*)(Zw + m16 * 72 + 0 * 32 + q * 8);
            A2[1].v = *(const short8*)(Zw + m16 * 72 + 1 * 32 + q * 8);

            f32x4 a2[4];
            #pragma unroll
            for (int nt = 0; nt < 4; ++nt) {
                a2[nt] = (f32x4){bb2[nt], bb2[nt], bb2[nt], bb2[nt]};
                short8 w0 = *(const short8*)(W2 + ((0 * 4 + nt) * 64 + lane) * 8);
                short8 w1f = *(const short8*)(W2 + ((1 * 4 + nt) * 64 + lane) * 8);
                a2[nt] = MFMA(A2[0].v, w0, a2[nt]);
                a2[nt] = MFMA(A2[1].v, w1f, a2[nt]);
            }

            ZTRANS(Zw, a2)
            FU A3[2];
            A3[0].v = *(const short8*)(Zw + m16 * 72 + 0 * 32 + q * 8);
            A3[1].v = *(const short8*)(Zw + m16 * 72 + 1 * 32 + q * 8);

            #pragma unroll
            for (int nt = 0; nt < 4; ++nt) {
                a3[mt][nt] = (f32x4){bb3[nt], bb3[nt], bb3[nt], bb3[nt]};
                short8 w0 = *(const short8*)(W3 + ((0 * 4 + nt) * 64 + lane) * 8);
                short8 w1f = *(const short8*)(W3 + ((1 * 4 + nt) * 64 + lane) * 8);
                a3[mt][nt] = MFMA(A3[0].v, w0, a3[mt][nt]);
                a3[mt][nt] = MFMA(A3[1].v, w1f, a3[mt][nt]);
            }
        }

        // segmented emit: in-place run-merge, one base addr per edge
        #pragma unroll
        for (int j = 0; j < 8; ++j) {
            int mt = j >> 2, r = j & 3;
            bool merge = (j < 7) && (dseq[j] == dseq[j + 1]);
            if (merge) {
                int mt2 = (j + 1) >> 2, r2 = (j + 1) & 3;
                #pragma unroll
                for (int nt = 0; nt < 4; ++nt) a3[mt2][nt][r2] += a3[mt][nt][r];
            } else {
                float* pbase = sums + (size_t)dseq[j] * 64 + m16;
                #pragma unroll
                for (int nt = 0; nt < 4; ++nt)
                    unsafeAtomicAdd(pbase + nt * 16, a3[mt][nt][r]);
            }
        }
    }
}

// ---------------------------------------------------------------------------
// edges_mfma: s2s (blocks < SPLIT) and a2s (blocks >= SPLIT) in one dispatch.
// ---------------------------------------------------------------------------
__global__ __launch_bounds__(256) void edges_mfma(
    const unsigned short* __restrict__ s_row, const unsigned short* __restrict__ a_row,
    const uint2* __restrict__ sdS, const int* __restrict__ sdstS,
    const uint2* __restrict__ sdA, const int* __restrict__ sdstA,
    const unsigned short* __restrict__ wtS, const unsigned short* __restrict__ wtA,
    const float* __restrict__ sb1, const float* __restrict__ sb2, const float* __restrict__ sb3,
    const float* __restrict__ ab1, const float* __restrict__ ab2, const float* __restrict__ ab3,
    const float* __restrict__ ps,
    float* __restrict__ sum_x, float* __restrict__ sum_u,
    int ES, int EA, int SPLIT)
{
    __shared__ __align__(16) unsigned short WT[7 * 2048];
    __shared__ __align__(16) unsigned short Z[4][16 * 72];

    int tid = threadIdx.x, bid = blockIdx.x;
    bool is_s = bid < SPLIT;
    const unsigned short* wt = is_s ? wtS : wtA;
    int wtn = is_s ? 7 * 2048 : 5 * 2048;
    for (int i = tid * 8; i < wtn; i += 256 * 8)
        *(short8*)(WT + i) = *(const short8*)(wt + i);
    __syncthreads();

    if (is_s)
        edge_path<3, 80>(s_row, sdS, sdstS, ps, WT, sb1, sb2, sb3,
                         sum_x, ES, bid, SPLIT, tid, &Z[0][0]);
    else
        edge_path<1, 16>(a_row, sdA, sdstA, ps, WT, ab1, ab2, ab3,
                         sum_u, EA, bid - SPLIT, gridDim.x - SPLIT, tid, &Z[0][0]);
}

// ---------------------------------------------------------------------------
// upd: fused gather (fp32 h/su/sxm/ps/x -> bf16 A-frags in-reg), K=224.
// Feature order matches prep1's permuted u_w1: [h | su | sxm | ps, x].
// ---------------------------------------------------------------------------
__global__ __launch_bounds__(256) void upd_mfma(
    const float* __restrict__ ps, const float* __restrict__ h,
    const float* __restrict__ x,
    const float* __restrict__ su, const float* __restrict__ sx,
    const int* __restrict__ cnt_s,
    const unsigned short* __restrict__ wtab,
    const float* __restrict__ b1, const float* __restrict__ b2,
    const float* __restrict__ b3,
    float* __restrict__ out, int NS)
{
    __shared__ __align__(16) unsigned short WT[11 * 2048];  // 44 KB
    __shared__ __align__(16) unsigned short Z[4][16 * 72];

    int tid = threadIdx.x;
    for (int i = tid * 8; i < 11 * 2048; i += 256 * 8)
        *(short8*)(WT + i) = *(const short8*)(wtab + i);
    __syncthreads();

    const unsigned short* W1 = WT;
    const unsigned short* W2 = WT + 7 * 2048;
    const unsigned short* W3 = WT + 9 * 2048;

    int wid = tid >> 6, lane = tid & 63, m16 = lane & 15, q = lane >> 4;
    unsigned short* Zw = &Z[wid][0];

    float bb1[4], bb2[4], bb3[4];
    #pragma unroll
    for (int nt = 0; nt < 4; ++nt) {
        bb1[nt] = b1[nt * 16 + m16];
        bb2[nt] = b2[nt * 16 + m16];
        bb3[nt] = b3[nt * 16 + m16];
    }

    int T = NS >> 4;
    for (int t = blockIdx.x * 4 + wid; t < T; t += gridDim.x * 4) {
        int n0 = t * 16;
        int n = n0 + m16;
        float rd = __builtin_amdgcn_rcpf(fmaxf((float)cnt_s[n], 1.0f));

        // A-frags: c=0,1 from h; 2,3 from su; 4,5 from sx*rd; 6 piecewise
        FU A[7];
        const float* hp = h + (size_t)n * 64;
        const float* sup = su + (size_t)n * 64;
        const float* sxp = sx + (size_t)n * 64;
        #pragma unroll
        for (int c = 0; c < 6; ++c) {
            const float* src = (c < 2) ? hp : (c < 4) ? sup : sxp;
            int base = (c & 1) * 32 + q * 8;
            float4 f0 = *(const float4*)(src + base);
            float4 f1 = *(const float4*)(src + base + 4);
            if (c >= 4) {
                f0.x *= rd; f0.y *= rd; f0.z *= rd; f0.w *= rd;
                f1.x *= rd; f1.y *= rd; f1.z *= rd; f1.w *= rd;
            }
            A[c].d[0] = pk2(f0.x, f0.y); A[c].d[1] = pk2(f0.z, f0.w);
            A[c].d[2] = pk2(f1.x, f1.y); A[c].d[3] = pk2(f1.z, f1.w);
        }
        A[6].d[0] = 0; A[6].d[1] = 0; A[6].d[2] = 0; A[6].d[3] = 0;
        if (q == 0) {
            float2 pp = *(const float2*)(ps + 2 * n);
            float4 x0 = *(const float4*)(x + 8 * n);
            float2 x1 = *(const float2*)(x + 8 * n + 4);
            A[6].d[0] = pk2(pp.x, pp.y);
            A[6].d[1] = pk2(x0.x, x0.y);
            A[6].d[2] = pk2(x0.z, x0.w);
            A[6].d[3] = pk2(x1.x, x1.y);
        } else if (q == 1) {
            float2 x2 = *(const float2*)(x + 8 * n + 6);
            A[6].d[0] = pk2(x2.x, x2.y);
        }

        f32x4 acc1[4];
        #pragma unroll
        for (int nt = 0; nt < 4; ++nt)
            acc1[nt] = (f32x4){bb1[nt], bb1[nt], bb1[nt], bb1[nt]};
        #pragma unroll
        for (int c = 0; c < 7; ++c)
            #pragma unroll
            for (int nt = 0; nt < 4; ++nt) {
                short8 wf = *(const short8*)(W1 + ((c * 4 + nt) * 64 + lane) * 8);
                acc1[nt] = MFMA(A[c].v, wf, acc1[nt]);
            }

        ZTRANS(Zw, acc1)
        FU A2[2];
        A2[0].v = *(const short8*)(Zw + m16 * 72 + 0 * 32 + q * 8);
        A2[1].v = *(const short8*)(Zw + m16 * 72 + 1 * 32 + q * 8);

        f32x4 a2[4];
        #pragma unroll
        for (int nt = 0; nt < 4; ++nt) {
            a2[nt] = (f32x4){bb2[nt], bb2[nt], bb2[nt], bb2[nt]};
            short8 w0 = *(const short8*)(W2 + ((0 * 4 + nt) * 64 + lane) * 8);
            short8 w1f = *(const short8*)(W2 + ((1 * 4 + nt) * 64 + lane) * 8);
            a2[nt] = MFMA(A2[0].v, w0, a2[nt]);
            a2[nt] = MFMA(A2[1].v, w1f, a2[nt]);
        }

        ZTRANS(Zw, a2)
        FU A3[2];
        A3[0].v = *(const short8*)(Zw + m16 * 72 + 0 * 32 + q * 8);
        A3[1].v = *(const short8*)(Zw + m16 * 72 + 1 * 32 + q * 8);

        f32x4 a3[4];
        #pragma unroll
        for (int nt = 0; nt < 4; ++nt) {
            a3[nt] = (f32x4){bb3[nt], bb3[nt], bb3[nt], bb3[nt]};
            short8 w0 = *(const short8*)(W3 + ((0 * 4 + nt) * 64 + lane) * 8);
            short8 w1f = *(const short8*)(W3 + ((1 * 4 + nt) * 64 + lane) * 8);
            a3[nt] = MFMA(A3[0].v, w0, a3[nt]);
            a3[nt] = MFMA(A3[1].v, w1f, a3[nt]);
        }

        #pragma unroll
        for (int nt = 0; nt < 4; ++nt)
            #pragma unroll
            for (int r = 0; r < 4; ++r)
                out[(size_t)(n0 + (q << 2) + r) * 64 + nt * 16 + m16] = a3[nt][r];
    }
}

extern "C" void kernel_launch(void* const* d_in, const int* in_sizes, int n_in,
                              void* d_out, int out_size, void* d_ws, size_t ws_size,
                              hipStream_t stream) {
    const float* pos_state  = (const float*)d_in[0];
    const float* pos_action = (const float*)d_in[1];
    const float* h          = (const float*)d_in[2];
    const float* x          = (const float*)d_in[3];
    const float* u          = (const float*)d_in[4];
    const int*   a2s_src    = (const int*)d_in[5];
    const int*   a2s_dst    = (const int*)d_in[6];
    const float* a2s_dis    = (const float*)d_in[7];
    const int*   s2s_src    = (const int*)d_in[8];
    const int*   s2s_dst    = (const int*)d_in[9];
    const float* s2s_dis    = (const float*)d_in[10];
    const float* u2h_w1 = (const float*)d_in[11]; const float* u2h_b1 = (const float*)d_in[12];
    const float* u2h_w2 = (const float*)d_in[13]; const float* u2h_b2 = (const float*)d_in[14];
    const float* u2h_w3 = (const float*)d_in[15]; const float* u2h_b3 = (const float*)d_in[16];
    const float* x2h_w1 = (const float*)d_in[17]; const float* x2h_b1 = (const float*)d_in[18];
    const float* x2h_w2 = (const float*)d_in[19]; const float* x2h_b2 = (const float*)d_in[20];
    const float* x2h_w3 = (const float*)d_in[21]; const float* x2h_b3 = (const float*)d_in[22];
    const float* upd_w1 = (const float*)d_in[23]; const float* upd_b1 = (const float*)d_in[24];
    const float* upd_w2 = (const float*)d_in[25]; const float* upd_b2 = (const float*)d_in[26];
    const float* upd_w3 = (const float*)d_in[27]; const float* upd_b3 = (const float*)d_in[28];

    int NS = in_sizes[0] / 2;
    int NA = in_sizes[1] / 2;
    int EA = in_sizes[5];
    int ES = in_sizes[8];
    int N2 = 2 * NS;
    int NB = (N2 + SCAN_CHUNK - 1) / SCAN_CHUNK;

    char* p = (char*)d_ws;
    int*   cnt2  = (int*)p;            p += (size_t)N2 * 4;       // cnt_s | cnt_a
    size_t zbytes = (size_t)(p - (char*)d_ws);                    // memset: cnt2 only
    float* sum_u = (float*)p;          p += (size_t)NS * 64 * 4;  // zeroed in scatter
    float* sum_x = (float*)p;          p += (size_t)NS * 64 * 4;
    int*   off2   = (int*)p;           p += (size_t)N2 * 4;
    int*   rank_s = (int*)p;           p += (size_t)ES * 4;
    int*   rank_a = (int*)p;           p += (size_t)EA * 4;
    uint2* sd_s   = (uint2*)p;         p += (size_t)ES * 8;       // {src,dis}
    int*   sdst_s = (int*)p;           p += (size_t)ES * 4;
    uint2* sd_a   = (uint2*)p;         p += (size_t)EA * 8;
    int*   sdst_a = (int*)p;           p += (size_t)EA * 4;
    unsigned short* s_row  = (unsigned short*)p; p += (size_t)NS * 80 * 2;
    unsigned short* a_row  = (unsigned short*)p; p += (size_t)NA * 16 * 2;
    int*   bsum   = (int*)p;           p += 128 * 4;
    unsigned short* wtab_s = (unsigned short*)p; p += 7 * 2048 * 2;
    unsigned short* wtab_a = (unsigned short*)p; p += 5 * 2048 * 2;
    unsigned short* wtab_u = (unsigned short*)p; p += 11 * 2048 * 2;
    (void)ws_size;

    int* cnt_s = cnt2;
    int* cnt_a = cnt2 + NS;
    int* off_s = off2;
    int* off_a = off2 + NS;

    hipMemsetAsync(d_ws, 0, zbytes, stream);

    const int MAINB = 2048;
    prep1<<<MAINB + 24, 256, 0, stream>>>(pos_state, pos_action, h, x, u,
                                          s2s_dst, a2s_dst, s_row, a_row,
                                          cnt_s, rank_s, cnt_a, rank_a,
                                          x2h_w1, x2h_w2, x2h_w3,
                                          u2h_w1, u2h_w2, u2h_w3,
                                          upd_w1, upd_w2, upd_w3,
                                          wtab_s, wtab_a, wtab_u,
                                          NS, NA, ES, EA, MAINB);
    scan_a<<<NB, 256, 0, stream>>>(cnt2, bsum, N2);
    scan_b<<<1, 128, 0, stream>>>(bsum, NB);
    scan_c<<<NB, 256, 0, stream>>>(cnt2, bsum, off2, N2, NS, ES);
    scatter_sort2<<<1024, 256, 0, stream>>>(s2s_src, s2s_dst, rank_s, off_s, s2s_dis,
                                            a2s_src, a2s_dst, rank_a, off_a, a2s_dis,
                                            sd_s, sdst_s, sd_a, sdst_a,
                                            sum_u, ES, EA, NS * 32);
    edges_mfma<<<1536, 256, 0, stream>>>(s_row, a_row,
                                         sd_s, sdst_s, sd_a, sdst_a,
                                         wtab_s, wtab_a,
                                         x2h_b1, x2h_b2, x2h_b3,
                                         u2h_b1, u2h_b2, u2h_b3,
                                         pos_state, sum_x, sum_u,
                                         ES, EA, 1120);
    upd_mfma<<<784, 256, 0, stream>>>(pos_state, h, x, sum_u, sum_x, cnt_s,
                                      wtab_u, upd_b1, upd_b2, upd_b3,
                                      (float*)d_out, NS);
}